// Round 9
// baseline (151.292 us; speedup 1.0000x reference)
//
#include <hip/hip_runtime.h>
#include <hip/hip_bf16.h>
#include <cmath>

#define DDIM 128
#define NPTS 3136   // 56*56
#define NCHUNK 196  // NPTS/16
#define QCHUNK 49   // chunks per n-quarter
#define BATCH 16
#define PROT 2000
#define PPAD 2048   // 16 tiles * 128

typedef __attribute__((ext_vector_type(8))) short bf16x8;
typedef __attribute__((ext_vector_type(4))) float f32x4;
typedef __attribute__((ext_vector_type(4))) unsigned int u32x4;

// ---- workspace layout (float/u32 slot indices) ----
#define WS_X2   0                      // 50176
#define WS_K1   50176                  // 131072 (16 b x 4 q x 2048)
#define WS_K2   181248                 // 131072
#define WS_PT   312320                 // 131072 slots (= 262144 shorts, 2048x128)
#define WS_XT   443392                 // 3211264 slots (= 16*196*4096 bytes)
#define WS_XFT  3654656                // 6422528 (16*3136*128 f32)
#define WS_MID  ((size_t)3654656 * 4)
#define WS_BIG  ((size_t)10077184 * 4)

// ---------------- bf16 helpers ----------------
__device__ inline unsigned short bf16rn(float a) {
    unsigned u = __float_as_uint(a);
    unsigned r = u + 0x7FFFu + ((u >> 16) & 1u);
    return (unsigned short)(r >> 16);
}

__device__ __forceinline__ void gload_lds16(const void* g, void* l) {
    __builtin_amdgcn_global_load_lds(
        (const __attribute__((address_space(1))) void*)g,
        (__attribute__((address_space(3))) void*)l, 16, 0, 0);
}
__device__ __forceinline__ void gload_lds4(const void* g, void* l) {
    __builtin_amdgcn_global_load_lds(
        (const __attribute__((address_space(1))) void*)g,
        (__attribute__((address_space(3))) void*)l, 4, 0, 0);
}

// ---------------- prototype pre-pass: pt[p][kk][32] bf16-rn ----------------
__global__ void pp_p(const float* __restrict__ proto, unsigned short* __restrict__ pt) {
    int p = blockIdx.x * blockDim.x + threadIdx.x; // 0..2047
    if (p >= PPAD) return;
    int ps = min(p, PROT - 1);
    const float* src = proto + (size_t)ps * DDIM;
    unsigned short* dst = pt + (size_t)p * 128;
    for (int j = 0; j < DDIM; ++j) dst[j] = bf16rn(src[j]);
}

// ---------------- x pre-pass ----------------
// xt chunk layout (4KB per 16-n chunk), wave-read-linear:
//   OFF(nl,kk,lg) = kk*1024 + lg*256 + nl*16
// x2 is PRE-BIASED+SCALED for the select kernel: x2' = 512*(|x|^2 + 512)
__global__ __launch_bounds__(256)
void pp_x(const float* __restrict__ x, unsigned short* __restrict__ xt,
          float* __restrict__ x2, float* __restrict__ xfT) {
    __shared__ float xs[DDIM][64];
    int b = blockIdx.y;
    int n0 = blockIdx.x * 64;
    int tid = threadIdx.x;
    {
        int r = tid >> 4, c = tid & 15;
        #pragma unroll
        for (int it = 0; it < 8; ++it) {
            int row = it * 16 + r;
            f32x4 v = *(const f32x4*)(x + ((size_t)(b * DDIM + row)) * NPTS + n0 + c * 4);
            *(f32x4*)(&xs[row][c * 4]) = v;
        }
    }
    __syncthreads();
    if (tid < 64) {
        float s = 0.f;
        #pragma unroll 8
        for (int d = 0; d < DDIM; ++d) { float v = xs[d][tid]; s = fmaf(v, v, s); }
        x2[b * NPTS + n0 + tid] = (s + 512.0f) * 512.0f;
    }
    int n = tid & 63, kk = tid >> 6;
    int nl = n & 15, ci = (n0 + n) >> 4;
    unsigned int hw[16];
    #pragma unroll
    for (int j = 0; j < 16; ++j) {
        unsigned short h0 = bf16rn(xs[kk * 32 + 2 * j][n]);
        unsigned short h1 = bf16rn(xs[kk * 32 + 2 * j + 1][n]);
        hw[j] = (unsigned)h0 | ((unsigned)h1 << 16);
    }
    char* cb = (char*)xt + ((size_t)b * NCHUNK + ci) * 4096;
    #pragma unroll
    for (int g = 0; g < 4; ++g)
        *(u32x4*)(cb + kk * 1024 + g * 256 + nl * 16) = *(u32x4*)(&hw[g * 4]);
    if (xfT) {
        float* fo = xfT + ((size_t)b * NPTS + n0 + n) * DDIM + kk * 32;
        #pragma unroll 8
        for (int j = 0; j < 32; ++j) fo[j] = xs[kk * 32 + j][n];
    }
}

// ---------------- main MFMA kernel (bf16 select, fixed-point packed keys) ----------------
// grid 1024 = (16 ptile x 16 b x 4 n-quarter) XCD-swizzled; block 512 = 8 waves
// = 4 psg x 2 nq. Counted-vmcnt(2) pipeline, 4 blocks/CU.
// key = cvt_u32(512*(x2+512) - 1024*dot) << 12 | n   (p2 dropped: constant per slot)
__global__ __launch_bounds__(512, 8)
void proto_mfma(const unsigned short* __restrict__ xt,
                const unsigned short* __restrict__ pt,
                const float* __restrict__ x2,
                unsigned* __restrict__ k1w, unsigned* __restrict__ k2w) {
    // hand-placed LDS: [0,4K) x2s | [4K,36K) As[4buf][2nq][4K] | [36K,38K) red
    __shared__ __align__(16) char LDS[38912];
    float* x2s = (float*)LDS;
    char*  AsB = LDS + 4096;
    unsigned* rk1 = (unsigned*)(LDS + 36864);   // [2][128]
    unsigned* rk2 = rk1 + 256;

    int lid = blockIdx.x;                      // 0..1023
    int sid = (lid & 7) * 128 + (lid >> 3);    // bijective XCD chunking (1024%8==0)
    int b = sid >> 6;                          // 2 b per XCD slice
    int rest = sid & 63;
    int pbase = (rest >> 2) * 128;
    int q = rest & 3;

    int tid = threadIdx.x;
    int lane = tid & 63, wave = tid >> 6;
    int psg = wave & 3, nq = wave >> 2;        // 4 p-groups x 2 n-streams
    int l15 = lane & 15, lg = lane >> 4;

    // B fragments: 2 ps x 4 kk = 32 VGPR, resident
    bf16x8 Bh[2][4];
    #pragma unroll
    for (int ps = 0; ps < 2; ++ps) {
        int p = pbase + psg * 32 + ps * 16 + l15;
        const unsigned short* bp = pt + (size_t)p * 128 + lg * 8;
        #pragma unroll
        for (int kk = 0; kk < 4; ++kk)
            Bh[ps][kk] = *(const bf16x8*)(bp + kk * 32);
    }

    const char* srcBase = (const char*)xt + ((size_t)b * NCHUNK + q * QCHUNK) * 4096;
    const char* aread = AsB + nq * 4096 + lane * 16;   // + u*8192 + kk*1024
    const int qOfs = q * (QCHUNK * 16);

    unsigned K1[2], K2[2];
    K1[0] = K1[1] = 0xFFFFFFFFu;
    K2[0] = K2[1] = 0xFFFFFFFFu;

    // ---- prologue: x2 quarter slice (2 dword-DMAs) + chunks T=0,1,2 ----
    {
        const float* xsrc = x2 + (size_t)b * NPTS + qOfs;
        #pragma unroll
        for (int r = 0; r < 2; ++r)
            gload_lds4(xsrc + min(r * 512 + wave * 64 + lane, QCHUNK * 16 - 1),
                       (char*)x2s + (r * 512 + wave * 64) * 4);
    }
    #pragma unroll
    for (int r = 0; r < 3; ++r)
        gload_lds16(srcBase + (size_t)(nq + 2 * r) * 4096 + psg * 1024 + (size_t)lane * 16,
                    AsB + r * 8192 + nq * 4096 + psg * 1024);

    // Body: 1 chunk-DMA per wave per iter; vmcnt(2) retires chunk T's loads.
    // LIVE guards the tracking on the tail iteration (nq=1 has only 24 chunks).
#define PMF_BODY(T, U, LIVE)                                                        \
    {                                                                               \
        asm volatile("s_waitcnt vmcnt(2)" ::: "memory");                            \
        __builtin_amdgcn_s_barrier();                                               \
        int cln = nq + 2 * ((T) + 3);                                               \
        cln = cln > QCHUNK - 1 ? QCHUNK - 1 : cln;                                  \
        gload_lds16(srcBase + (size_t)cln * 4096 + psg * 1024 + (size_t)lane * 16,  \
                    AsB + (((U) + 3) & 3) * 8192 + nq * 4096 + psg * 1024);         \
        int cl = nq + 2 * (T);                                                      \
        f32x4 xv = *(const f32x4*)&x2s[min(cl, QCHUNK - 1) * 16 + lg * 4];          \
        const char* ar = aread + (U) * 8192;                                        \
        f32x4 acc0 = {0.f, 0.f, 0.f, 0.f};                                          \
        f32x4 acc1 = {0.f, 0.f, 0.f, 0.f};                                          \
        __builtin_amdgcn_s_setprio(1);                                              \
        _Pragma("unroll")                                                           \
        for (int kk = 0; kk < 4; ++kk) {                                            \
            bf16x8 Ah = *(const bf16x8*)(ar + kk * 1024);                           \
            acc0 = __builtin_amdgcn_mfma_f32_16x16x32_bf16(Ah, Bh[0][kk], acc0, 0, 0, 0); \
            acc1 = __builtin_amdgcn_mfma_f32_16x16x32_bf16(Ah, Bh[1][kk], acc1, 0, 0, 0); \
        }                                                                           \
        __builtin_amdgcn_s_setprio(0);                                              \
        if (LIVE) {                                                                 \
            int nb = qOfs + cl * 16 + lg * 4;                                       \
            _Pragma("unroll")                                                       \
            for (int rr = 0; rr < 4; ++rr) {                                        \
                float f0 = fmaf(acc0[rr], -1024.f, xv[rr]);                         \
                float f1 = fmaf(acc1[rr], -1024.f, xv[rr]);                         \
                unsigned k0 = ((unsigned)f0 << 12) | (unsigned)(nb + rr);           \
                unsigned k1_ = ((unsigned)f1 << 12) | (unsigned)(nb + rr);          \
                K2[0] = min(K2[0], max(K1[0], k0)); K1[0] = min(K1[0], k0);         \
                K2[1] = min(K2[1], max(K1[1], k1_)); K1[1] = min(K1[1], k1_);       \
            }                                                                       \
        }                                                                           \
    }

    #pragma unroll 1
    for (int t0 = 0; t0 < 24; t0 += 4) {
        PMF_BODY(t0 + 0, 0, true)
        PMF_BODY(t0 + 1, 1, true)
        PMF_BODY(t0 + 2, 2, true)
        PMF_BODY(t0 + 3, 3, true)
    }
    PMF_BODY(24, 0, (nq == 0))   // tail: nq=1 stream has only 24 chunks
#undef PMF_BODY
    __syncthreads();   // full drain before reduction

    // ---- reduce across the 4 row-groups (lanes l, l+16, l+32, l+48) ----
    #pragma unroll
    for (int m = 16; m <= 32; m <<= 1) {
        #pragma unroll
        for (int ps = 0; ps < 2; ++ps) {
            unsigned c1 = (unsigned)__shfl_xor((int)K1[ps], m, 64);
            unsigned c2 = (unsigned)__shfl_xor((int)K2[ps], m, 64);
            unsigned w  = max(K1[ps], c1);
            K1[ps] = min(K1[ps], c1);
            K2[ps] = min(w, min(K2[ps], c2));
        }
    }

    if (lg == 0) {
        #pragma unroll
        for (int ps = 0; ps < 2; ++ps) {
            int idx = psg * 32 + ps * 16 + l15;
            rk1[nq * 128 + idx] = K1[ps];
            rk2[nq * 128 + idx] = K2[ps];
        }
    }
    __syncthreads();
    if (tid < 128) {
        unsigned a1 = rk1[tid], a2 = rk2[tid];
        unsigned b1 = rk1[128 + tid], b2 = rk2[128 + tid];
        size_t o = ((size_t)b * 4 + q) * PPAD + pbase + tid;
        k1w[o] = min(a1, b1);
        k2w[o] = min(max(a1, b1), min(a2, b2));
    }
}

// ---------------- exact fp32 fixup over ALL 8 quarter candidates ----------------
// Coverage: top-2 per quarter (disjoint n ranges). A miss requires the true fp32
// argmin to be bf16-rank>=3 WITHIN ITS QUARTER -- strictly safer than round 7's
// passing half-top-2 scheme (quarter rank <= half rank).
template<int MODE>
__global__ __launch_bounds__(256)
void fixup(const float* __restrict__ x, const float* __restrict__ xfT,
           const float* __restrict__ proto,
           const unsigned* __restrict__ k1w, const unsigned* __restrict__ k2w,
           float* __restrict__ out) {
    int tid = threadIdx.x;
    int lane = tid & 63, wv = tid >> 6;
    long long pair = (long long)blockIdx.x * 4 + wv;
    if (pair >= (long long)BATCH * PROT) return;
    int b = (int)(pair / PROT), p = (int)(pair % PROT);
    int cand[8];
    #pragma unroll
    for (int qq = 0; qq < 4; ++qq) {
        cand[qq]     = (int)(k1w[((size_t)b * 4 + qq) * PPAD + p] & 0xFFFu);
        cand[4 + qq] = (int)(k2w[((size_t)b * 4 + qq) * PPAD + p] & 0xFFFu);
    }
    int d0 = lane, d1 = lane + 64;
    float pa0 = proto[(size_t)p * DDIM + d0], pa1 = proto[(size_t)p * DDIM + d1];
    float sp2 = pa0 * pa0 + pa1 * pa1;
    float f0[8], f1[8], sxp[8], sx2[8];
    #pragma unroll
    for (int c = 0; c < 8; ++c) {
        int n = cand[c];
        float v0, v1;
        if (MODE == 0) {
            const float* f = xfT + ((size_t)b * NPTS + n) * DDIM;
            v0 = f[d0]; v1 = f[d1];
        } else {
            const float* xb = x + (size_t)b * DDIM * NPTS;
            v0 = xb[(size_t)d0 * NPTS + n]; v1 = xb[(size_t)d1 * NPTS + n];
        }
        f0[c] = v0; f1[c] = v1;
        sxp[c] = v0 * pa0 + v1 * pa1;
        sx2[c] = v0 * v0 + v1 * v1;
    }
    #pragma unroll
    for (int m = 1; m < 64; m <<= 1) {
        sp2 += __shfl_xor(sp2, m, 64);
        #pragma unroll
        for (int c = 0; c < 8; ++c) {
            sxp[c] += __shfl_xor(sxp[c], m, 64);
            sx2[c] += __shfl_xor(sx2[c], m, 64);
        }
    }
    float bd = 3e38f; int bn = 0x7FFFFFFF; int bc = 0;
    #pragma unroll
    for (int c = 0; c < 8; ++c) {
        float d2 = fmaxf(sx2[c] + sp2 - 2.f * sxp[c], 0.f);
        bool w = (d2 < bd) || (d2 == bd && cand[c] < bn);
        bd = w ? d2 : bd;
        bn = w ? cand[c] : bn;
        bc = w ? c : bc;
    }
    float dm = sqrtf(bd);
    float sim = logf((dm + 1.0f) / (dm + 1e-7f));
    if (lane == 0) {
        out[(size_t)b * PROT + p] = sim;
        out[(size_t)BATCH * PROT + (size_t)b * PROT + p] = dm;
    }
    float o0 = f0[0], o1 = f1[0];
    #pragma unroll
    for (int c = 1; c < 8; ++c) {
        o0 = (bc == c) ? f0[c] : o0;
        o1 = (bc == c) ? f1[c] : o1;
    }
    float* fo = out + (size_t)2 * BATCH * PROT + ((size_t)b * PROT + p) * DDIM;
    fo[d0] = o0;
    fo[d1] = o1;
}

// ================= fallback fp32 path (round-1, known-good) =================
#define TP 64
#define TN 64
__global__ void p2_kernel(const float* __restrict__ proto, float* __restrict__ p2) {
    int p = blockIdx.x * blockDim.x + threadIdx.x;
    if (p >= PROT) return;
    const float4* pr = reinterpret_cast<const float4*>(proto + (size_t)p * DDIM);
    float s = 0.f;
    #pragma unroll
    for (int i = 0; i < DDIM / 4; ++i) {
        float4 v = pr[i];
        s += v.x * v.x + v.y * v.y + v.z * v.z + v.w * v.w;
    }
    p2[p] = s;
}
__global__ void x2_kernel(const float* __restrict__ x, float* __restrict__ x2) {
    int idx = blockIdx.x * blockDim.x + threadIdx.x;
    if (idx >= BATCH * NPTS) return;
    int b = idx / NPTS, n = idx - b * NPTS;
    const float* xp = x + (size_t)b * DDIM * NPTS + n;
    float s = 0.f;
    #pragma unroll 8
    for (int d = 0; d < DDIM; ++d) { float v = xp[(size_t)d * NPTS]; s += v * v; }
    x2[idx] = s;
}
__global__ __launch_bounds__(256, 2)
void proto_main(const float* __restrict__ x, const float* __restrict__ proto,
                const float* __restrict__ p2, const float* __restrict__ x2,
                float* __restrict__ out) {
    __shared__ __align__(16) float xs[DDIM][TN];
    __shared__ __align__(16) float pst[DDIM][TP];
    __shared__ float p2s[TP];
    __shared__ float x2s[TN];
    __shared__ float red_d2[16][TP];
    __shared__ int   red_n[16][TP];
    __shared__ int   bestn_s[TP];
    const int b = blockIdx.y;
    const int pbase = blockIdx.x * TP;
    const int tid = threadIdx.x;
    {
        #pragma unroll
        for (int it = 0; it < (TP * DDIM / 4) / 256; ++it) {
            int idx = it * 256 + tid;
            int p = idx / (DDIM / 4);
            int dq = idx - p * (DDIM / 4);
            int gp = min(pbase + p, PROT - 1);
            float4 v = reinterpret_cast<const float4*>(proto)[(size_t)gp * (DDIM / 4) + dq];
            pst[dq * 4 + 0][p] = v.x; pst[dq * 4 + 1][p] = v.y;
            pst[dq * 4 + 2][p] = v.z; pst[dq * 4 + 3][p] = v.w;
        }
        if (tid < TP) p2s[tid] = p2[min(pbase + tid, PROT - 1)];
    }
    const int tn = tid >> 4;
    const int tp = tid & 15;
    float best[4]; int bestn[4];
    #pragma unroll
    for (int j = 0; j < 4; ++j) { best[j] = 1e30f; bestn[j] = 0; }
    for (int n0 = 0; n0 < NPTS; n0 += TN) {
        __syncthreads();
        {
            int r = tid >> 4, c = tid & 15;
            #pragma unroll
            for (int it = 0; it < 8; ++it) {
                int row = it * 16 + r;
                float4 v = *reinterpret_cast<const float4*>(
                    x + ((size_t)(b * DDIM + row)) * NPTS + n0 + c * 4);
                *reinterpret_cast<float4*>(&xs[row][c * 4]) = v;
            }
        }
        if (tid < TN) x2s[tid] = x2[b * NPTS + n0 + tid];
        __syncthreads();
        float acc[4][4];
        #pragma unroll
        for (int i = 0; i < 4; ++i)
            #pragma unroll
            for (int j = 0; j < 4; ++j) acc[i][j] = 0.f;
        #pragma unroll 16
        for (int d = 0; d < DDIM; ++d) {
            const float4 a = *reinterpret_cast<const float4*>(&xs[d][tn * 4]);
            const float4 bv = *reinterpret_cast<const float4*>(&pst[d][tp * 4]);
            const float av[4] = {a.x, a.y, a.z, a.w};
            const float bw[4] = {bv.x, bv.y, bv.z, bv.w};
            #pragma unroll
            for (int i = 0; i < 4; ++i)
                #pragma unroll
                for (int j = 0; j < 4; ++j) acc[i][j] = fmaf(av[i], bw[j], acc[i][j]);
        }
        #pragma unroll
        for (int i = 0; i < 4; ++i) {
            float xv = x2s[tn * 4 + i];
            int n = n0 + tn * 4 + i;
            #pragma unroll
            for (int j = 0; j < 4; ++j) {
                float d2 = xv + p2s[tp * 4 + j] - 2.0f * acc[i][j];
                if (d2 < best[j]) { best[j] = d2; bestn[j] = n; }
            }
        }
    }
    #pragma unroll
    for (int j = 0; j < 4; ++j) {
        red_d2[tn][tp * 4 + j] = best[j];
        red_n[tn][tp * 4 + j] = bestn[j];
    }
    __syncthreads();
    if (tid < TP) {
        float bd = red_d2[0][tid]; int bn = red_n[0][tid];
        #pragma unroll
        for (int t = 1; t < 16; ++t) {
            float dv = red_d2[t][tid]; int nv = red_n[t][tid];
            if (dv < bd || (dv == bd && nv < bn)) { bd = dv; bn = nv; }
        }
        int gp = pbase + tid;
        if (gp < PROT) {
            float d2c = fmaxf(bd, 0.f);
            float dmin = sqrtf(d2c);
            float sim = logf((dmin + 1.0f) / (dmin + 1e-7f));
            out[(size_t)b * PROT + gp] = sim;
            out[(size_t)BATCH * PROT + (size_t)b * PROT + gp] = dmin;
        }
        bestn_s[tid] = bn;
    }
    __syncthreads();
    {
        int pl = tid >> 2, dbase = (tid & 3) * 32;
        int gp = pbase + pl;
        if (gp < PROT) {
            int n = bestn_s[pl];
            float* dst = out + (size_t)2 * BATCH * PROT + ((size_t)(b * PROT + gp)) * DDIM + dbase;
            const float* src = x + ((size_t)(b * DDIM + dbase)) * NPTS + n;
            #pragma unroll 8
            for (int d = 0; d < 32; ++d) dst[d] = src[(size_t)d * NPTS];
        }
    }
}

extern "C" void kernel_launch(void* const* d_in, const int* in_sizes, int n_in,
                              void* d_out, int out_size, void* d_ws, size_t ws_size,
                              hipStream_t stream) {
    const float* x = (const float*)d_in[0];       // [16,128,56,56]
    const float* proto = (const float*)d_in[1];   // [1,2000,128]
    float* out = (float*)d_out;
    float* ws = (float*)d_ws;

    if (ws_size >= WS_MID) {
        bool big = (ws_size >= WS_BIG);
        float* x2 = ws + WS_X2;
        unsigned* k1w = (unsigned*)(ws + WS_K1);
        unsigned* k2w = (unsigned*)(ws + WS_K2);
        unsigned short* pt = (unsigned short*)(ws + WS_PT);
        unsigned short* xt = (unsigned short*)(ws + WS_XT);
        float* xfT = big ? (ws + WS_XFT) : nullptr;

        pp_p<<<PPAD / 256, 256, 0, stream>>>(proto, pt);
        pp_x<<<dim3(NPTS / 64, BATCH), 256, 0, stream>>>(x, xt, x2, xfT);
        proto_mfma<<<1024, 512, 0, stream>>>(xt, pt, x2, k1w, k2w);
        if (big)
            fixup<0><<<(BATCH * PROT) / 4, 256, 0, stream>>>(x, xfT, proto, k1w, k2w, out);
        else
            fixup<1><<<(BATCH * PROT) / 4, 256, 0, stream>>>(x, nullptr, proto, k1w, k2w, out);
    } else {
        float* p2 = ws;
        float* x2 = ws + 2048;
        p2_kernel<<<(PROT + 255) / 256, 256, 0, stream>>>(proto, p2);
        x2_kernel<<<(BATCH * NPTS + 255) / 256, 256, 0, stream>>>(x, x2);
        dim3 grid((PROT + TP - 1) / TP, BATCH);
        proto_main<<<grid, 256, 0, stream>>>(x, proto, p2, x2, out);
    }
}

// Round 10
// 106.337 us; speedup vs baseline: 1.4228x; 1.4228x over previous
//
#include <hip/hip_runtime.h>
#include <hip/hip_bf16.h>
#include <cmath>

#define DDIM 128
#define NPTS 3136   // 56*56
#define NCHUNK 196  // NPTS/16
#define QCHUNK 49   // chunks per n-quarter
#define BATCH 16
#define PROT 2000
#define PPAD 2048   // 32 tiles * 64

typedef __attribute__((ext_vector_type(8))) short bf16x8;
typedef __attribute__((ext_vector_type(4))) float f32x4;
typedef __attribute__((ext_vector_type(4))) unsigned int u32x4;

// ---- workspace layout (float/u32 slot indices) ----
#define WS_X2   0                      // 50176
#define WS_K1   50176                  // 131072 (16 b x 4 q x 2048)
#define WS_K2   181248                 // 131072
#define WS_PT   312320                 // 131072 slots (= 262144 shorts, 2048x128)
#define WS_XT   443392                 // 3211264 slots (= 16*196*4096 bytes)
#define WS_XFT  3654656                // 6422528 (16*3136*128 f32)
#define WS_MID  ((size_t)3654656 * 4)
#define WS_BIG  ((size_t)10077184 * 4)

// ---------------- bf16 helpers ----------------
__device__ inline unsigned short bf16rn(float a) {
    unsigned u = __float_as_uint(a);
    unsigned r = u + 0x7FFFu + ((u >> 16) & 1u);
    return (unsigned short)(r >> 16);
}

__device__ __forceinline__ void gload_lds16(const void* g, void* l) {
    __builtin_amdgcn_global_load_lds(
        (const __attribute__((address_space(1))) void*)g,
        (__attribute__((address_space(3))) void*)l, 16, 0, 0);
}
__device__ __forceinline__ void gload_lds4(const void* g, void* l) {
    __builtin_amdgcn_global_load_lds(
        (const __attribute__((address_space(1))) void*)g,
        (__attribute__((address_space(3))) void*)l, 4, 0, 0);
}

// ---------------- prototype pre-pass: pt[p][kk][32] bf16-rn ----------------
__global__ void pp_p(const float* __restrict__ proto, unsigned short* __restrict__ pt) {
    int p = blockIdx.x * blockDim.x + threadIdx.x; // 0..2047
    if (p >= PPAD) return;
    int ps = min(p, PROT - 1);
    const float* src = proto + (size_t)ps * DDIM;
    unsigned short* dst = pt + (size_t)p * 128;
    for (int j = 0; j < DDIM; ++j) dst[j] = bf16rn(src[j]);
}

// ---------------- x pre-pass ----------------
// xt chunk layout (4KB per 16-n chunk), wave-read-linear:
//   OFF(nl,kk,lg) = kk*1024 + lg*256 + nl*16
// x2 is PRE-BIASED+SCALED for the select kernel: x2' = 512*(|x|^2 + 512)
__global__ __launch_bounds__(256)
void pp_x(const float* __restrict__ x, unsigned short* __restrict__ xt,
          float* __restrict__ x2, float* __restrict__ xfT) {
    __shared__ float xs[DDIM][64];
    int b = blockIdx.y;
    int n0 = blockIdx.x * 64;
    int tid = threadIdx.x;
    {
        int r = tid >> 4, c = tid & 15;
        #pragma unroll
        for (int it = 0; it < 8; ++it) {
            int row = it * 16 + r;
            f32x4 v = *(const f32x4*)(x + ((size_t)(b * DDIM + row)) * NPTS + n0 + c * 4);
            *(f32x4*)(&xs[row][c * 4]) = v;
        }
    }
    __syncthreads();
    if (tid < 64) {
        float s = 0.f;
        #pragma unroll 8
        for (int d = 0; d < DDIM; ++d) { float v = xs[d][tid]; s = fmaf(v, v, s); }
        x2[b * NPTS + n0 + tid] = (s + 512.0f) * 512.0f;
    }
    int n = tid & 63, kk = tid >> 6;
    int nl = n & 15, ci = (n0 + n) >> 4;
    unsigned int hw[16];
    #pragma unroll
    for (int j = 0; j < 16; ++j) {
        unsigned short h0 = bf16rn(xs[kk * 32 + 2 * j][n]);
        unsigned short h1 = bf16rn(xs[kk * 32 + 2 * j + 1][n]);
        hw[j] = (unsigned)h0 | ((unsigned)h1 << 16);
    }
    char* cb = (char*)xt + ((size_t)b * NCHUNK + ci) * 4096;
    #pragma unroll
    for (int g = 0; g < 4; ++g)
        *(u32x4*)(cb + kk * 1024 + g * 256 + nl * 16) = *(u32x4*)(&hw[g * 4]);
    if (xfT) {
        float* fo = xfT + ((size_t)b * NPTS + n0 + n) * DDIM + kk * 32;
        #pragma unroll 8
        for (int j = 0; j < 32; ++j) fo[j] = xs[kk * 32 + j][n];
    }
}

// ---------------- main MFMA kernel (bf16 select, fixed-point packed keys) ----------------
// grid 2048 = (32 ptile x 16 b x 4 n-quarter) XCD-swizzled; block 512 = 8 waves
// = 4 psg x 2 nq; p-tile 64, ps=1 per wave (B = 4 NAMED bf16x8 = 16 VGPR).
// Counted-vmcnt(2) pipeline; ~40 VGPR demand -> no spill at (512,8).
__global__ __launch_bounds__(512, 8)
void proto_mfma(const unsigned short* __restrict__ xt,
                const unsigned short* __restrict__ pt,
                const float* __restrict__ x2,
                unsigned* __restrict__ k1w, unsigned* __restrict__ k2w) {
    // hand-placed LDS: [0,4K) x2s | [4K,36K) As[4buf][2nq][4K] | [36K,37K) red
    __shared__ __align__(16) char LDS[37888];
    float* x2s = (float*)LDS;
    char*  AsB = LDS + 4096;
    unsigned* rk1 = (unsigned*)(LDS + 36864);   // [2][64]
    unsigned* rk2 = rk1 + 128;

    int lid = blockIdx.x;                      // 0..2047
    int sid = (lid & 7) * 256 + (lid >> 3);    // bijective XCD chunking (2048%8==0)
    int b = sid >> 7;                          // 2 b per XCD slice
    int rest = sid & 127;
    int pbase = (rest >> 2) * 64;              // 32 ptiles
    int q = rest & 3;

    int tid = threadIdx.x;
    int lane = tid & 63, wave = tid >> 6;
    int psg = wave & 3, nq = wave >> 2;        // 4 p-groups x 2 n-streams
    int l15 = lane & 15, lg = lane >> 4;

    // B fragments: 4 named bf16x8 (16 VGPR), resident
    const unsigned short* bp = pt + (size_t)(pbase + psg * 16 + l15) * 128 + lg * 8;
    bf16x8 B0 = *(const bf16x8*)(bp);
    bf16x8 B1 = *(const bf16x8*)(bp + 32);
    bf16x8 B2 = *(const bf16x8*)(bp + 64);
    bf16x8 B3 = *(const bf16x8*)(bp + 96);

    const char* srcBase = (const char*)xt + ((size_t)b * NCHUNK + q * QCHUNK) * 4096;
    const char* aread = AsB + nq * 4096 + lane * 16;   // + u*8192 + kk*1024
    const int qOfs = q * (QCHUNK * 16);

    unsigned K1 = 0xFFFFFFFFu, K2 = 0xFFFFFFFFu;

    // ---- prologue: x2 quarter slice (2 dword-DMAs) + chunks T=0,1,2 ----
    {
        const float* xsrc = x2 + (size_t)b * NPTS + qOfs;
        #pragma unroll
        for (int r = 0; r < 2; ++r)
            gload_lds4(xsrc + min(r * 512 + wave * 64 + lane, QCHUNK * 16 - 1),
                       (char*)x2s + (r * 512 + wave * 64) * 4);
    }
    #pragma unroll
    for (int r = 0; r < 3; ++r)
        gload_lds16(srcBase + (size_t)(nq + 2 * r) * 4096 + psg * 1024 + (size_t)lane * 16,
                    AsB + r * 8192 + nq * 4096 + psg * 1024);

    // Body: 1 chunk-DMA per wave per iter; vmcnt(2) retires chunk T's loads.
    // LIVE guards tracking on the tail iteration (nq=1 stream has only 24 chunks).
#define PMF_BODY(T, U, LIVE)                                                        \
    {                                                                               \
        asm volatile("s_waitcnt vmcnt(2)" ::: "memory");                            \
        __builtin_amdgcn_s_barrier();                                               \
        int cln = nq + 2 * ((T) + 3);                                               \
        cln = cln > QCHUNK - 1 ? QCHUNK - 1 : cln;                                  \
        gload_lds16(srcBase + (size_t)cln * 4096 + psg * 1024 + (size_t)lane * 16,  \
                    AsB + (((U) + 3) & 3) * 8192 + nq * 4096 + psg * 1024);         \
        int cl = nq + 2 * (T);                                                      \
        f32x4 xv = *(const f32x4*)&x2s[min(cl, QCHUNK - 1) * 16 + lg * 4];          \
        const char* ar = aread + (U) * 8192;                                        \
        f32x4 acc = {0.f, 0.f, 0.f, 0.f};                                           \
        __builtin_amdgcn_s_setprio(1);                                              \
        acc = __builtin_amdgcn_mfma_f32_16x16x32_bf16(*(const bf16x8*)(ar),        B0, acc, 0, 0, 0); \
        acc = __builtin_amdgcn_mfma_f32_16x16x32_bf16(*(const bf16x8*)(ar + 1024), B1, acc, 0, 0, 0); \
        acc = __builtin_amdgcn_mfma_f32_16x16x32_bf16(*(const bf16x8*)(ar + 2048), B2, acc, 0, 0, 0); \
        acc = __builtin_amdgcn_mfma_f32_16x16x32_bf16(*(const bf16x8*)(ar + 3072), B3, acc, 0, 0, 0); \
        __builtin_amdgcn_s_setprio(0);                                              \
        if (LIVE) {                                                                 \
            int nb = qOfs + cl * 16 + lg * 4;                                       \
            _Pragma("unroll")                                                       \
            for (int rr = 0; rr < 4; ++rr) {                                        \
                float f0 = fmaf(acc[rr], -1024.f, xv[rr]);                          \
                unsigned k0 = ((unsigned)f0 << 12) | (unsigned)(nb + rr);           \
                K2 = min(K2, max(K1, k0));                                          \
                K1 = min(K1, k0);                                                   \
            }                                                                       \
        }                                                                           \
    }

    #pragma unroll 1
    for (int t0 = 0; t0 < 24; t0 += 4) {
        PMF_BODY(t0 + 0, 0, true)
        PMF_BODY(t0 + 1, 1, true)
        PMF_BODY(t0 + 2, 2, true)
        PMF_BODY(t0 + 3, 3, true)
    }
    PMF_BODY(24, 0, (nq == 0))   // tail: nq=1 stream has only 24 chunks
#undef PMF_BODY
    __syncthreads();   // full drain before reduction

    // ---- reduce across the 4 row-groups (lanes l, l+16, l+32, l+48) ----
    #pragma unroll
    for (int m = 16; m <= 32; m <<= 1) {
        unsigned c1 = (unsigned)__shfl_xor((int)K1, m, 64);
        unsigned c2 = (unsigned)__shfl_xor((int)K2, m, 64);
        unsigned w  = max(K1, c1);
        K1 = min(K1, c1);
        K2 = min(w, min(K2, c2));
    }

    if (lg == 0) {
        int idx = psg * 16 + l15;
        rk1[nq * 64 + idx] = K1;
        rk2[nq * 64 + idx] = K2;
    }
    __syncthreads();
    if (tid < 64) {
        unsigned a1 = rk1[tid], a2 = rk2[tid];
        unsigned b1 = rk1[64 + tid], b2 = rk2[64 + tid];
        size_t o = ((size_t)b * 4 + q) * PPAD + pbase + tid;
        k1w[o] = min(a1, b1);
        k2w[o] = min(max(a1, b1), min(a2, b2));
    }
}

// ---------------- exact fp32 fixup over ALL 8 quarter candidates ----------------
// Coverage: top-2 per quarter (disjoint n ranges). A miss requires the true fp32
// argmin to be bf16-rank>=3 WITHIN ITS QUARTER.
template<int MODE>
__global__ __launch_bounds__(256)
void fixup(const float* __restrict__ x, const float* __restrict__ xfT,
           const float* __restrict__ proto,
           const unsigned* __restrict__ k1w, const unsigned* __restrict__ k2w,
           float* __restrict__ out) {
    int tid = threadIdx.x;
    int lane = tid & 63, wv = tid >> 6;
    long long pair = (long long)blockIdx.x * 4 + wv;
    if (pair >= (long long)BATCH * PROT) return;
    int b = (int)(pair / PROT), p = (int)(pair % PROT);
    int cand[8];
    #pragma unroll
    for (int qq = 0; qq < 4; ++qq) {
        cand[qq]     = (int)(k1w[((size_t)b * 4 + qq) * PPAD + p] & 0xFFFu);
        cand[4 + qq] = (int)(k2w[((size_t)b * 4 + qq) * PPAD + p] & 0xFFFu);
    }
    int d0 = lane, d1 = lane + 64;
    float pa0 = proto[(size_t)p * DDIM + d0], pa1 = proto[(size_t)p * DDIM + d1];
    float sp2 = pa0 * pa0 + pa1 * pa1;
    float f0[8], f1[8], sxp[8], sx2[8];
    #pragma unroll
    for (int c = 0; c < 8; ++c) {
        int n = cand[c];
        float v0, v1;
        if (MODE == 0) {
            const float* f = xfT + ((size_t)b * NPTS + n) * DDIM;
            v0 = f[d0]; v1 = f[d1];
        } else {
            const float* xb = x + (size_t)b * DDIM * NPTS;
            v0 = xb[(size_t)d0 * NPTS + n]; v1 = xb[(size_t)d1 * NPTS + n];
        }
        f0[c] = v0; f1[c] = v1;
        sxp[c] = v0 * pa0 + v1 * pa1;
        sx2[c] = v0 * v0 + v1 * v1;
    }
    #pragma unroll
    for (int m = 1; m < 64; m <<= 1) {
        sp2 += __shfl_xor(sp2, m, 64);
        #pragma unroll
        for (int c = 0; c < 8; ++c) {
            sxp[c] += __shfl_xor(sxp[c], m, 64);
            sx2[c] += __shfl_xor(sx2[c], m, 64);
        }
    }
    float bd = 3e38f; int bn = 0x7FFFFFFF; int bc = 0;
    #pragma unroll
    for (int c = 0; c < 8; ++c) {
        float d2 = fmaxf(sx2[c] + sp2 - 2.f * sxp[c], 0.f);
        bool w = (d2 < bd) || (d2 == bd && cand[c] < bn);
        bd = w ? d2 : bd;
        bn = w ? cand[c] : bn;
        bc = w ? c : bc;
    }
    float dm = sqrtf(bd);
    float sim = logf((dm + 1.0f) / (dm + 1e-7f));
    if (lane == 0) {
        out[(size_t)b * PROT + p] = sim;
        out[(size_t)BATCH * PROT + (size_t)b * PROT + p] = dm;
    }
    float o0 = f0[0], o1 = f1[0];
    #pragma unroll
    for (int c = 1; c < 8; ++c) {
        o0 = (bc == c) ? f0[c] : o0;
        o1 = (bc == c) ? f1[c] : o1;
    }
    float* fo = out + (size_t)2 * BATCH * PROT + ((size_t)b * PROT + p) * DDIM;
    fo[d0] = o0;
    fo[d1] = o1;
}

// ================= fallback fp32 path (round-1, known-good) =================
#define TP 64
#define TN 64
__global__ void p2_kernel(const float* __restrict__ proto, float* __restrict__ p2) {
    int p = blockIdx.x * blockDim.x + threadIdx.x;
    if (p >= PROT) return;
    const float4* pr = reinterpret_cast<const float4*>(proto + (size_t)p * DDIM);
    float s = 0.f;
    #pragma unroll
    for (int i = 0; i < DDIM / 4; ++i) {
        float4 v = pr[i];
        s += v.x * v.x + v.y * v.y + v.z * v.z + v.w * v.w;
    }
    p2[p] = s;
}
__global__ void x2_kernel(const float* __restrict__ x, float* __restrict__ x2) {
    int idx = blockIdx.x * blockDim.x + threadIdx.x;
    if (idx >= BATCH * NPTS) return;
    int b = idx / NPTS, n = idx - b * NPTS;
    const float* xp = x + (size_t)b * DDIM * NPTS + n;
    float s = 0.f;
    #pragma unroll 8
    for (int d = 0; d < DDIM; ++d) { float v = xp[(size_t)d * NPTS]; s += v * v; }
    x2[idx] = s;
}
__global__ __launch_bounds__(256, 2)
void proto_main(const float* __restrict__ x, const float* __restrict__ proto,
                const float* __restrict__ p2, const float* __restrict__ x2,
                float* __restrict__ out) {
    __shared__ __align__(16) float xs[DDIM][TN];
    __shared__ __align__(16) float pst[DDIM][TP];
    __shared__ float p2s[TP];
    __shared__ float x2s[TN];
    __shared__ float red_d2[16][TP];
    __shared__ int   red_n[16][TP];
    __shared__ int   bestn_s[TP];
    const int b = blockIdx.y;
    const int pbase = blockIdx.x * TP;
    const int tid = threadIdx.x;
    {
        #pragma unroll
        for (int it = 0; it < (TP * DDIM / 4) / 256; ++it) {
            int idx = it * 256 + tid;
            int p = idx / (DDIM / 4);
            int dq = idx - p * (DDIM / 4);
            int gp = min(pbase + p, PROT - 1);
            float4 v = reinterpret_cast<const float4*>(proto)[(size_t)gp * (DDIM / 4) + dq];
            pst[dq * 4 + 0][p] = v.x; pst[dq * 4 + 1][p] = v.y;
            pst[dq * 4 + 2][p] = v.z; pst[dq * 4 + 3][p] = v.w;
        }
        if (tid < TP) p2s[tid] = p2[min(pbase + tid, PROT - 1)];
    }
    const int tn = tid >> 4;
    const int tp = tid & 15;
    float best[4]; int bestn[4];
    #pragma unroll
    for (int j = 0; j < 4; ++j) { best[j] = 1e30f; bestn[j] = 0; }
    for (int n0 = 0; n0 < NPTS; n0 += TN) {
        __syncthreads();
        {
            int r = tid >> 4, c = tid & 15;
            #pragma unroll
            for (int it = 0; it < 8; ++it) {
                int row = it * 16 + r;
                float4 v = *reinterpret_cast<const float4*>(
                    x + ((size_t)(b * DDIM + row)) * NPTS + n0 + c * 4);
                *reinterpret_cast<float4*>(&xs[row][c * 4]) = v;
            }
        }
        if (tid < TN) x2s[tid] = x2[b * NPTS + n0 + tid];
        __syncthreads();
        float acc[4][4];
        #pragma unroll
        for (int i = 0; i < 4; ++i)
            #pragma unroll
            for (int j = 0; j < 4; ++j) acc[i][j] = 0.f;
        #pragma unroll 16
        for (int d = 0; d < DDIM; ++d) {
            const float4 a = *reinterpret_cast<const float4*>(&xs[d][tn * 4]);
            const float4 bv = *reinterpret_cast<const float4*>(&pst[d][tp * 4]);
            const float av[4] = {a.x, a.y, a.z, a.w};
            const float bw[4] = {bv.x, bv.y, bv.z, bv.w};
            #pragma unroll
            for (int i = 0; i < 4; ++i)
                #pragma unroll
                for (int j = 0; j < 4; ++j) acc[i][j] = fmaf(av[i], bw[j], acc[i][j]);
        }
        #pragma unroll
        for (int i = 0; i < 4; ++i) {
            float xv = x2s[tn * 4 + i];
            int n = n0 + tn * 4 + i;
            #pragma unroll
            for (int j = 0; j < 4; ++j) {
                float d2 = xv + p2s[tp * 4 + j] - 2.0f * acc[i][j];
                if (d2 < best[j]) { best[j] = d2; bestn[j] = n; }
            }
        }
    }
    #pragma unroll
    for (int j = 0; j < 4; ++j) {
        red_d2[tn][tp * 4 + j] = best[j];
        red_n[tn][tp * 4 + j] = bestn[j];
    }
    __syncthreads();
    if (tid < TP) {
        float bd = red_d2[0][tid]; int bn = red_n[0][tid];
        #pragma unroll
        for (int t = 1; t < 16; ++t) {
            float dv = red_d2[t][tid]; int nv = red_n[t][tid];
            if (dv < bd || (dv == bd && nv < bn)) { bd = dv; bn = nv; }
        }
        int gp = pbase + tid;
        if (gp < PROT) {
            float d2c = fmaxf(bd, 0.f);
            float dmin = sqrtf(d2c);
            float sim = logf((dmin + 1.0f) / (dmin + 1e-7f));
            out[(size_t)b * PROT + gp] = sim;
            out[(size_t)BATCH * PROT + (size_t)b * PROT + gp] = dmin;
        }
        bestn_s[tid] = bn;
    }
    __syncthreads();
    {
        int pl = tid >> 2, dbase = (tid & 3) * 32;
        int gp = pbase + pl;
        if (gp < PROT) {
            int n = bestn_s[pl];
            float* dst = out + (size_t)2 * BATCH * PROT + ((size_t)(b * PROT + gp)) * DDIM + dbase;
            const float* src = x + ((size_t)(b * DDIM + dbase)) * NPTS + n;
            #pragma unroll 8
            for (int d = 0; d < 32; ++d) dst[d] = src[(size_t)d * NPTS];
        }
    }
}

extern "C" void kernel_launch(void* const* d_in, const int* in_sizes, int n_in,
                              void* d_out, int out_size, void* d_ws, size_t ws_size,
                              hipStream_t stream) {
    const float* x = (const float*)d_in[0];       // [16,128,56,56]
    const float* proto = (const float*)d_in[1];   // [1,2000,128]
    float* out = (float*)d_out;
    float* ws = (float*)d_ws;

    if (ws_size >= WS_MID) {
        bool big = (ws_size >= WS_BIG);
        float* x2 = ws + WS_X2;
        unsigned* k1w = (unsigned*)(ws + WS_K1);
        unsigned* k2w = (unsigned*)(ws + WS_K2);
        unsigned short* pt = (unsigned short*)(ws + WS_PT);
        unsigned short* xt = (unsigned short*)(ws + WS_XT);
        float* xfT = big ? (ws + WS_XFT) : nullptr;

        pp_p<<<PPAD / 256, 256, 0, stream>>>(proto, pt);
        pp_x<<<dim3(NPTS / 64, BATCH), 256, 0, stream>>>(x, xt, x2, xfT);
        proto_mfma<<<2048, 512, 0, stream>>>(xt, pt, x2, k1w, k2w);
        if (big)
            fixup<0><<<(BATCH * PROT) / 4, 256, 0, stream>>>(x, xfT, proto, k1w, k2w, out);
        else
            fixup<1><<<(BATCH * PROT) / 4, 256, 0, stream>>>(x, nullptr, proto, k1w, k2w, out);
    } else {
        float* p2 = ws;
        float* x2 = ws + 2048;
        p2_kernel<<<(PROT + 255) / 256, 256, 0, stream>>>(proto, p2);
        x2_kernel<<<(BATCH * NPTS + 255) / 256, 256, 0, stream>>>(x, x2);
        dim3 grid((PROT + TP - 1) / TP, BATCH);
        proto_main<<<grid, 256, 0, stream>>>(x, proto, p2, x2, out);
    }
}

// Round 11
// 89.468 us; speedup vs baseline: 1.6910x; 1.1886x over previous
//
#include <hip/hip_runtime.h>
#include <hip/hip_bf16.h>
#include <cmath>

#define DDIM 128
#define NPTS 3136   // 56*56
#define NCHUNK 196  // NPTS/16
#define QCHUNK 49   // chunks per n-quarter
#define BATCH 16
#define PROT 2000
#define PPAD 2048   // 32 tiles * 64

typedef __attribute__((ext_vector_type(8))) short bf16x8;
typedef __attribute__((ext_vector_type(4))) float f32x4;
typedef __attribute__((ext_vector_type(4))) unsigned int u32x4;

// ---- workspace layout (float/u32 slot indices) ----
#define WS_X2   0                      // 50176
#define WS_K1   50176                  // 131072 (16 b x 4 q x 2048)
#define WS_K2   181248                 // 131072
#define WS_PT   312320                 // 131072 slots (= 262144 shorts, 2048x128)
#define WS_XT   443392                 // 3211264 slots (= 16*196*4096 bytes)
#define WS_XFT  3654656                // 6422528 (16*3136*128 f32)
#define WS_MID  ((size_t)3654656 * 4)
#define WS_BIG  ((size_t)10077184 * 4)

// ---------------- bf16 helpers ----------------
__device__ inline unsigned short bf16rn(float a) {
    unsigned u = __float_as_uint(a);
    unsigned r = u + 0x7FFFu + ((u >> 16) & 1u);
    return (unsigned short)(r >> 16);
}

__device__ __forceinline__ void gload_lds16(const void* g, void* l) {
    __builtin_amdgcn_global_load_lds(
        (const __attribute__((address_space(1))) void*)g,
        (__attribute__((address_space(3))) void*)l, 16, 0, 0);
}
__device__ __forceinline__ void gload_lds4(const void* g, void* l) {
    __builtin_amdgcn_global_load_lds(
        (const __attribute__((address_space(1))) void*)g,
        (__attribute__((address_space(3))) void*)l, 4, 0, 0);
}

// ---------------- prototype pre-pass: pt[p][kk][32] bf16-rn ----------------
__global__ void pp_p(const float* __restrict__ proto, unsigned short* __restrict__ pt) {
    int p = blockIdx.x * blockDim.x + threadIdx.x; // 0..2047
    if (p >= PPAD) return;
    int ps = min(p, PROT - 1);
    const float* src = proto + (size_t)ps * DDIM;
    unsigned short* dst = pt + (size_t)p * 128;
    for (int j = 0; j < DDIM; ++j) dst[j] = bf16rn(src[j]);
}

// ---------------- x pre-pass ----------------
// xt chunk layout (4KB per 16-n chunk), wave-read-linear:
//   OFF(nl,kk,lg) = kk*1024 + lg*256 + nl*16
// x2 is PRE-BIASED+SCALED for the select kernel: x2' = 512*(|x|^2 + 512)
__global__ __launch_bounds__(256)
void pp_x(const float* __restrict__ x, unsigned short* __restrict__ xt,
          float* __restrict__ x2, float* __restrict__ xfT) {
    __shared__ float xs[DDIM][64];
    int b = blockIdx.y;
    int n0 = blockIdx.x * 64;
    int tid = threadIdx.x;
    {
        int r = tid >> 4, c = tid & 15;
        #pragma unroll
        for (int it = 0; it < 8; ++it) {
            int row = it * 16 + r;
            f32x4 v = *(const f32x4*)(x + ((size_t)(b * DDIM + row)) * NPTS + n0 + c * 4);
            *(f32x4*)(&xs[row][c * 4]) = v;
        }
    }
    __syncthreads();
    if (tid < 64) {
        float s = 0.f;
        #pragma unroll 8
        for (int d = 0; d < DDIM; ++d) { float v = xs[d][tid]; s = fmaf(v, v, s); }
        x2[b * NPTS + n0 + tid] = (s + 512.0f) * 512.0f;
    }
    int n = tid & 63, kk = tid >> 6;
    int nl = n & 15, ci = (n0 + n) >> 4;
    unsigned int hw[16];
    #pragma unroll
    for (int j = 0; j < 16; ++j) {
        unsigned short h0 = bf16rn(xs[kk * 32 + 2 * j][n]);
        unsigned short h1 = bf16rn(xs[kk * 32 + 2 * j + 1][n]);
        hw[j] = (unsigned)h0 | ((unsigned)h1 << 16);
    }
    char* cb = (char*)xt + ((size_t)b * NCHUNK + ci) * 4096;
    #pragma unroll
    for (int g = 0; g < 4; ++g)
        *(u32x4*)(cb + kk * 1024 + g * 256 + nl * 16) = *(u32x4*)(&hw[g * 4]);
    if (xfT) {
        float* fo = xfT + ((size_t)b * NPTS + n0 + n) * DDIM + kk * 32;
        #pragma unroll
        for (int g = 0; g < 8; ++g) {
            f32x4 v;
            v[0] = xs[kk * 32 + g * 4 + 0][n];
            v[1] = xs[kk * 32 + g * 4 + 1][n];
            v[2] = xs[kk * 32 + g * 4 + 2][n];
            v[3] = xs[kk * 32 + g * 4 + 3][n];
            *(f32x4*)(fo + g * 4) = v;
        }
    }
}

// ---------------- main MFMA kernel (bf16 select, fixed-point packed keys) ----------------
// grid 2048 = (32 ptile x 16 b x 4 n-quarter) XCD-swizzled; block 256 = 4 waves
// = 4 psg, ONE n-stream of 49 chunks. 8 blocks/CU = 32 waves (one full fill).
// Counted-vmcnt(2): chunk t staged at body t-3; vmcnt then barrier => all slices landed.
__global__ __launch_bounds__(256, 8)
void proto_mfma(const unsigned short* __restrict__ xt,
                const unsigned short* __restrict__ pt,
                const float* __restrict__ x2,
                unsigned* __restrict__ k1w, unsigned* __restrict__ k2w) {
    // hand-placed LDS: [0,4K) x2s (784 used) | [4K,20K) As[4buf][4K]
    __shared__ __align__(16) char LDS[20480];
    float* x2s = (float*)LDS;
    char*  AsB = LDS + 4096;

    int lid = blockIdx.x;                      // 0..2047
    int sid = (lid & 7) * 256 + (lid >> 3);    // bijective XCD chunking (2048%8==0)
    int b = sid >> 7;                          // 2 b per XCD slice
    int rest = sid & 127;
    int pbase = (rest >> 2) * 64;              // 32 ptiles
    int q = rest & 3;

    int tid = threadIdx.x;
    int lane = tid & 63, psg = tid >> 6;       // 4 p-groups, shared n-stream
    int l15 = lane & 15, lg = lane >> 4;

    // B fragments: 4 named bf16x8 (16 VGPR), resident
    const unsigned short* bp = pt + (size_t)(pbase + psg * 16 + l15) * 128 + lg * 8;
    bf16x8 B0 = *(const bf16x8*)(bp);
    bf16x8 B1 = *(const bf16x8*)(bp + 32);
    bf16x8 B2 = *(const bf16x8*)(bp + 64);
    bf16x8 B3 = *(const bf16x8*)(bp + 96);

    const char* srcBase = (const char*)xt + ((size_t)b * NCHUNK + q * QCHUNK) * 4096;
    const char* aread = AsB + lane * 16;       // + u*4096 + kk*1024
    const int qOfs = q * (QCHUNK * 16);

    unsigned K1 = 0xFFFFFFFFu, K2 = 0xFFFFFFFFu;

    // ---- prologue: x2 quarter slice (4 dword-DMAs, clamped) + chunks 0,1,2 ----
    {
        const float* xsrc = x2 + (size_t)b * NPTS + qOfs;
        #pragma unroll
        for (int r = 0; r < 4; ++r)
            gload_lds4(xsrc + min(r * 256 + psg * 64 + lane, QCHUNK * 16 - 1),
                       (char*)x2s + (r * 256 + psg * 64) * 4);
    }
    #pragma unroll
    for (int r = 0; r < 3; ++r)
        gload_lds16(srcBase + (size_t)r * 4096 + psg * 1024 + (size_t)lane * 16,
                    AsB + r * 4096 + psg * 1024);

    // Body: 1 chunk-DMA per wave per body; vmcnt(2) retires chunk T's loads
    // (in-order; x2 loads issued first retire first). Barrier AFTER the wait
    // => every wave's psg-slice of chunk T has landed for all readers.
#define PMF_BODY(T, U)                                                              \
    {                                                                               \
        asm volatile("s_waitcnt vmcnt(2)" ::: "memory");                            \
        __builtin_amdgcn_s_barrier();                                               \
        int cln = (T) + 3;                                                          \
        cln = cln > QCHUNK - 1 ? QCHUNK - 1 : cln;                                  \
        gload_lds16(srcBase + (size_t)cln * 4096 + psg * 1024 + (size_t)lane * 16,  \
                    AsB + (((U) + 3) & 3) * 4096 + psg * 1024);                     \
        f32x4 xv = *(const f32x4*)&x2s[(T) * 16 + lg * 4];                          \
        const char* ar = aread + (U) * 4096;                                        \
        f32x4 acc = {0.f, 0.f, 0.f, 0.f};                                           \
        __builtin_amdgcn_s_setprio(1);                                              \
        acc = __builtin_amdgcn_mfma_f32_16x16x32_bf16(*(const bf16x8*)(ar),        B0, acc, 0, 0, 0); \
        acc = __builtin_amdgcn_mfma_f32_16x16x32_bf16(*(const bf16x8*)(ar + 1024), B1, acc, 0, 0, 0); \
        acc = __builtin_amdgcn_mfma_f32_16x16x32_bf16(*(const bf16x8*)(ar + 2048), B2, acc, 0, 0, 0); \
        acc = __builtin_amdgcn_mfma_f32_16x16x32_bf16(*(const bf16x8*)(ar + 3072), B3, acc, 0, 0, 0); \
        __builtin_amdgcn_s_setprio(0);                                              \
        int nb = qOfs + (T) * 16 + lg * 4;                                          \
        _Pragma("unroll")                                                           \
        for (int rr = 0; rr < 4; ++rr) {                                            \
            float f0 = fmaf(acc[rr], -1024.f, xv[rr]);                              \
            unsigned k0 = ((unsigned)f0 << 12) | (unsigned)(nb + rr);               \
            K2 = min(K2, max(K1, k0));                                              \
            K1 = min(K1, k0);                                                       \
        }                                                                           \
    }

    #pragma unroll 1
    for (int t0 = 0; t0 < 48; t0 += 4) {
        PMF_BODY(t0 + 0, 0)
        PMF_BODY(t0 + 1, 1)
        PMF_BODY(t0 + 2, 2)
        PMF_BODY(t0 + 3, 3)
    }
    PMF_BODY(48, 0)
#undef PMF_BODY

    // ---- reduce across the 4 row-groups (lanes l, l+16, l+32, l+48) ----
    #pragma unroll
    for (int m = 16; m <= 32; m <<= 1) {
        unsigned c1 = (unsigned)__shfl_xor((int)K1, m, 64);
        unsigned c2 = (unsigned)__shfl_xor((int)K2, m, 64);
        unsigned w  = max(K1, c1);
        K1 = min(K1, c1);
        K2 = min(w, min(K2, c2));
    }
    // each wave owns 16 distinct p -> direct global write, no cross-wave reduce
    if (lg == 0) {
        size_t o = ((size_t)b * 4 + q) * PPAD + pbase + psg * 16 + l15;
        k1w[o] = K1;
        k2w[o] = K2;
    }
}

// ---------------- exact fp32 fixup: derive half-top-2 (4 candidates) ----------------
// Quarter top-2s merge EXACTLY into half top-2s (disjoint n ranges):
//   top2(half) = top2(union(top2(qA), top2(qB))). Round-7-proven coverage,
//   now with 60x finer key quantization. d2 formula bit-identical to r9/r10.
template<int MODE>
__global__ __launch_bounds__(256)
void fixup(const float* __restrict__ x, const float* __restrict__ xfT,
           const float* __restrict__ proto,
           const unsigned* __restrict__ k1w, const unsigned* __restrict__ k2w,
           float* __restrict__ out) {
    int tid = threadIdx.x;
    int lane = tid & 63, wv = tid >> 6;
    long long pair = (long long)blockIdx.x * 4 + wv;
    if (pair >= (long long)BATCH * PROT) return;
    int b = (int)(pair / PROT), p = (int)(pair % PROT);
    unsigned a0 = k1w[((size_t)b * 4 + 0) * PPAD + p];
    unsigned a1 = k1w[((size_t)b * 4 + 1) * PPAD + p];
    unsigned a2 = k1w[((size_t)b * 4 + 2) * PPAD + p];
    unsigned a3 = k1w[((size_t)b * 4 + 3) * PPAD + p];
    unsigned c0 = k2w[((size_t)b * 4 + 0) * PPAD + p];
    unsigned c1 = k2w[((size_t)b * 4 + 1) * PPAD + p];
    unsigned c2 = k2w[((size_t)b * 4 + 2) * PPAD + p];
    unsigned c3 = k2w[((size_t)b * 4 + 3) * PPAD + p];
    int cand[4];
    cand[0] = (int)(min(a0, a1) & 0xFFFu);
    cand[1] = (int)(min(max(a0, a1), min(c0, c1)) & 0xFFFu);
    cand[2] = (int)(min(a2, a3) & 0xFFFu);
    cand[3] = (int)(min(max(a2, a3), min(c2, c3)) & 0xFFFu);

    int d0 = lane, d1 = lane + 64;
    float pa0 = proto[(size_t)p * DDIM + d0], pa1 = proto[(size_t)p * DDIM + d1];
    float sp2 = pa0 * pa0 + pa1 * pa1;
    float f0[4], f1[4], sxp[4], sx2[4];
    #pragma unroll
    for (int c = 0; c < 4; ++c) {
        int n = cand[c];
        float v0, v1;
        if (MODE == 0) {
            const float* f = xfT + ((size_t)b * NPTS + n) * DDIM;
            v0 = f[d0]; v1 = f[d1];
        } else {
            const float* xb = x + (size_t)b * DDIM * NPTS;
            v0 = xb[(size_t)d0 * NPTS + n]; v1 = xb[(size_t)d1 * NPTS + n];
        }
        f0[c] = v0; f1[c] = v1;
        sxp[c] = v0 * pa0 + v1 * pa1;
        sx2[c] = v0 * v0 + v1 * v1;
    }
    #pragma unroll
    for (int m = 1; m < 64; m <<= 1) {
        sp2 += __shfl_xor(sp2, m, 64);
        #pragma unroll
        for (int c = 0; c < 4; ++c) {
            sxp[c] += __shfl_xor(sxp[c], m, 64);
            sx2[c] += __shfl_xor(sx2[c], m, 64);
        }
    }
    float bd = 3e38f; int bn = 0x7FFFFFFF; int bc = 0;
    #pragma unroll
    for (int c = 0; c < 4; ++c) {
        float d2 = fmaxf(sx2[c] + sp2 - 2.f * sxp[c], 0.f);
        bool w = (d2 < bd) || (d2 == bd && cand[c] < bn);
        bd = w ? d2 : bd;
        bn = w ? cand[c] : bn;
        bc = w ? c : bc;
    }
    float dm = sqrtf(bd);
    float sim = logf((dm + 1.0f) / (dm + 1e-7f));
    if (lane == 0) {
        out[(size_t)b * PROT + p] = sim;
        out[(size_t)BATCH * PROT + (size_t)b * PROT + p] = dm;
    }
    float o0 = f0[0], o1 = f1[0];
    #pragma unroll
    for (int c = 1; c < 4; ++c) {
        o0 = (bc == c) ? f0[c] : o0;
        o1 = (bc == c) ? f1[c] : o1;
    }
    float* fo = out + (size_t)2 * BATCH * PROT + ((size_t)b * PROT + p) * DDIM;
    fo[d0] = o0;
    fo[d1] = o1;
}

// ================= fallback fp32 path (round-1, known-good) =================
#define TP 64
#define TN 64
__global__ void p2_kernel(const float* __restrict__ proto, float* __restrict__ p2) {
    int p = blockIdx.x * blockDim.x + threadIdx.x;
    if (p >= PROT) return;
    const float4* pr = reinterpret_cast<const float4*>(proto + (size_t)p * DDIM);
    float s = 0.f;
    #pragma unroll
    for (int i = 0; i < DDIM / 4; ++i) {
        float4 v = pr[i];
        s += v.x * v.x + v.y * v.y + v.z * v.z + v.w * v.w;
    }
    p2[p] = s;
}
__global__ void x2_kernel(const float* __restrict__ x, float* __restrict__ x2) {
    int idx = blockIdx.x * blockDim.x + threadIdx.x;
    if (idx >= BATCH * NPTS) return;
    int b = idx / NPTS, n = idx - b * NPTS;
    const float* xp = x + (size_t)b * DDIM * NPTS + n;
    float s = 0.f;
    #pragma unroll 8
    for (int d = 0; d < DDIM; ++d) { float v = xp[(size_t)d * NPTS]; s += v * v; }
    x2[idx] = s;
}
__global__ __launch_bounds__(256, 2)
void proto_main(const float* __restrict__ x, const float* __restrict__ proto,
                const float* __restrict__ p2, const float* __restrict__ x2,
                float* __restrict__ out) {
    __shared__ __align__(16) float xs[DDIM][TN];
    __shared__ __align__(16) float pst[DDIM][TP];
    __shared__ float p2s[TP];
    __shared__ float x2s[TN];
    __shared__ float red_d2[16][TP];
    __shared__ int   red_n[16][TP];
    __shared__ int   bestn_s[TP];
    const int b = blockIdx.y;
    const int pbase = blockIdx.x * TP;
    const int tid = threadIdx.x;
    {
        #pragma unroll
        for (int it = 0; it < (TP * DDIM / 4) / 256; ++it) {
            int idx = it * 256 + tid;
            int p = idx / (DDIM / 4);
            int dq = idx - p * (DDIM / 4);
            int gp = min(pbase + p, PROT - 1);
            float4 v = reinterpret_cast<const float4*>(proto)[(size_t)gp * (DDIM / 4) + dq];
            pst[dq * 4 + 0][p] = v.x; pst[dq * 4 + 1][p] = v.y;
            pst[dq * 4 + 2][p] = v.z; pst[dq * 4 + 3][p] = v.w;
        }
        if (tid < TP) p2s[tid] = p2[min(pbase + tid, PROT - 1)];
    }
    const int tn = tid >> 4;
    const int tp = tid & 15;
    float best[4]; int bestn[4];
    #pragma unroll
    for (int j = 0; j < 4; ++j) { best[j] = 1e30f; bestn[j] = 0; }
    for (int n0 = 0; n0 < NPTS; n0 += TN) {
        __syncthreads();
        {
            int r = tid >> 4, c = tid & 15;
            #pragma unroll
            for (int it = 0; it < 8; ++it) {
                int row = it * 16 + r;
                float4 v = *reinterpret_cast<const float4*>(
                    x + ((size_t)(b * DDIM + row)) * NPTS + n0 + c * 4);
                *reinterpret_cast<float4*>(&xs[row][c * 4]) = v;
            }
        }
        if (tid < TN) x2s[tid] = x2[b * NPTS + n0 + tid];
        __syncthreads();
        float acc[4][4];
        #pragma unroll
        for (int i = 0; i < 4; ++i)
            #pragma unroll
            for (int j = 0; j < 4; ++j) acc[i][j] = 0.f;
        #pragma unroll 16
        for (int d = 0; d < DDIM; ++d) {
            const float4 a = *reinterpret_cast<const float4*>(&xs[d][tn * 4]);
            const float4 bv = *reinterpret_cast<const float4*>(&pst[d][tp * 4]);
            const float av[4] = {a.x, a.y, a.z, a.w};
            const float bw[4] = {bv.x, bv.y, bv.z, bv.w};
            #pragma unroll
            for (int i = 0; i < 4; ++i)
                #pragma unroll
                for (int j = 0; j < 4; ++j) acc[i][j] = fmaf(av[i], bw[j], acc[i][j]);
        }
        #pragma unroll
        for (int i = 0; i < 4; ++i) {
            float xv = x2s[tn * 4 + i];
            int n = n0 + tn * 4 + i;
            #pragma unroll
            for (int j = 0; j < 4; ++j) {
                float d2 = xv + p2s[tp * 4 + j] - 2.0f * acc[i][j];
                if (d2 < best[j]) { best[j] = d2; bestn[j] = n; }
            }
        }
    }
    #pragma unroll
    for (int j = 0; j < 4; ++j) {
        red_d2[tn][tp * 4 + j] = best[j];
        red_n[tn][tp * 4 + j] = bestn[j];
    }
    __syncthreads();
    if (tid < TP) {
        float bd = red_d2[0][tid]; int bn = red_n[0][tid];
        #pragma unroll
        for (int t = 1; t < 16; ++t) {
            float dv = red_d2[t][tid]; int nv = red_n[t][tid];
            if (dv < bd || (dv == bd && nv < bn)) { bd = dv; bn = nv; }
        }
        int gp = pbase + tid;
        if (gp < PROT) {
            float d2c = fmaxf(bd, 0.f);
            float dmin = sqrtf(d2c);
            float sim = logf((dmin + 1.0f) / (dmin + 1e-7f));
            out[(size_t)b * PROT + gp] = sim;
            out[(size_t)BATCH * PROT + (size_t)b * PROT + gp] = dmin;
        }
        bestn_s[tid] = bn;
    }
    __syncthreads();
    {
        int pl = tid >> 2, dbase = (tid & 3) * 32;
        int gp = pbase + pl;
        if (gp < PROT) {
            int n = bestn_s[pl];
            float* dst = out + (size_t)2 * BATCH * PROT + ((size_t)(b * PROT + gp)) * DDIM + dbase;
            const float* src = x + ((size_t)(b * DDIM + dbase)) * NPTS + n;
            #pragma unroll 8
            for (int d = 0; d < 32; ++d) dst[d] = src[(size_t)d * NPTS];
        }
    }
}

extern "C" void kernel_launch(void* const* d_in, const int* in_sizes, int n_in,
                              void* d_out, int out_size, void* d_ws, size_t ws_size,
                              hipStream_t stream) {
    const float* x = (const float*)d_in[0];       // [16,128,56,56]
    const float* proto = (const float*)d_in[1];   // [1,2000,128]
    float* out = (float*)d_out;
    float* ws = (float*)d_ws;

    if (ws_size >= WS_MID) {
        bool big = (ws_size >= WS_BIG);
        float* x2 = ws + WS_X2;
        unsigned* k1w = (unsigned*)(ws + WS_K1);
        unsigned* k2w = (unsigned*)(ws + WS_K2);
        unsigned short* pt = (unsigned short*)(ws + WS_PT);
        unsigned short* xt = (unsigned short*)(ws + WS_XT);
        float* xfT = big ? (ws + WS_XFT) : nullptr;

        pp_p<<<PPAD / 256, 256, 0, stream>>>(proto, pt);
        pp_x<<<dim3(NPTS / 64, BATCH), 256, 0, stream>>>(x, xt, x2, xfT);
        proto_mfma<<<2048, 256, 0, stream>>>(xt, pt, x2, k1w, k2w);
        if (big)
            fixup<0><<<(BATCH * PROT) / 4, 256, 0, stream>>>(x, xfT, proto, k1w, k2w, out);
        else
            fixup<1><<<(BATCH * PROT) / 4, 256, 0, stream>>>(x, nullptr, proto, k1w, k2w, out);
    } else {
        float* p2 = ws;
        float* x2 = ws + 2048;
        p2_kernel<<<(PROT + 255) / 256, 256, 0, stream>>>(proto, p2);
        x2_kernel<<<(BATCH * NPTS + 255) / 256, 256, 0, stream>>>(x, x2);
        dim3 grid((PROT + TP - 1) / TP, BATCH);
        proto_main<<<grid, 256, 0, stream>>>(x, proto, p2, x2, out);
    }
}

// Round 14
// 81.719 us; speedup vs baseline: 1.8514x; 1.0948x over previous
//
#include <hip/hip_runtime.h>
#include <hip/hip_bf16.h>
#include <cmath>

#define DDIM 128
#define NPTS 3136   // 56*56
#define NCHUNK 196  // NPTS/16
#define QCHUNK 49   // chunks per n-quarter
#define BATCH 16
#define PROT 2000
#define PPAD 2048   // 32 tiles * 64

typedef __attribute__((ext_vector_type(8))) short bf16x8;
typedef __attribute__((ext_vector_type(4))) float f32x4;
typedef __attribute__((ext_vector_type(4))) unsigned int u32x4;

// ---- workspace layout (float/u32 slot indices) ----
#define WS_X2   0                      // 50176
#define WS_K1   50176                  // 131072 (16 b x 4 q x 2048)
#define WS_K2   181248                 // 131072
#define WS_PT   312320                 // 131072 slots (= 262144 shorts, 2048x128)
#define WS_XT   443392                 // 3211264 slots (= 16*196*4096 bytes)
#define WS_XFT  3654656                // 6422528 (16*3136*128 f32)
#define WS_MID  ((size_t)3654656 * 4)
#define WS_BIG  ((size_t)10077184 * 4)

// ---------------- bf16 helpers ----------------
__device__ inline unsigned short bf16rn(float a) {
    unsigned u = __float_as_uint(a);
    unsigned r = u + 0x7FFFu + ((u >> 16) & 1u);
    return (unsigned short)(r >> 16);
}

__device__ __forceinline__ void gload_lds16(const void* g, void* l) {
    __builtin_amdgcn_global_load_lds(
        (const __attribute__((address_space(1))) void*)g,
        (__attribute__((address_space(3))) void*)l, 16, 0, 0);
}
__device__ __forceinline__ void gload_lds4(const void* g, void* l) {
    __builtin_amdgcn_global_load_lds(
        (const __attribute__((address_space(1))) void*)g,
        (__attribute__((address_space(3))) void*)l, 4, 0, 0);
}

// ---------------- fused pre-pass ----------------
// grid (50, 16). Blocks x<49: x tile pre-pass (as r11). Blocks x==49, y<8:
// prototype split pt[p][kk][32] bf16-rn (block-uniform branch; no barrier skew).
// xt chunk layout (4KB per 16-n chunk), wave-read-linear:
//   OFF(nl,kk,lg) = kk*1024 + lg*256 + nl*16
// x2 is PRE-BIASED+SCALED for the select kernel: x2' = 512*(|x|^2 + 512)
__global__ __launch_bounds__(256)
void pp_fused(const float* __restrict__ x, const float* __restrict__ proto,
              unsigned short* __restrict__ xt, unsigned short* __restrict__ pt,
              float* __restrict__ x2, float* __restrict__ xfT) {
    int tid = threadIdx.x;
    if (blockIdx.x == 49) {               // prototype part: 8 blocks x 256 = 2048
        int by = blockIdx.y;
        if (by >= 8) return;
        int p = by * 256 + tid;           // 0..2047
        int ps = min(p, PROT - 1);
        const float* src = proto + (size_t)ps * DDIM;
        unsigned short* dst = pt + (size_t)p * 128;
        for (int j = 0; j < DDIM; ++j) dst[j] = bf16rn(src[j]);
        return;
    }
    __shared__ float xs[DDIM][64];
    int b = blockIdx.y;
    int n0 = blockIdx.x * 64;
    {
        int r = tid >> 4, c = tid & 15;
        #pragma unroll
        for (int it = 0; it < 8; ++it) {
            int row = it * 16 + r;
            f32x4 v = *(const f32x4*)(x + ((size_t)(b * DDIM + row)) * NPTS + n0 + c * 4);
            *(f32x4*)(&xs[row][c * 4]) = v;
        }
    }
    __syncthreads();
    if (tid < 64) {
        float s = 0.f;
        #pragma unroll 8
        for (int d = 0; d < DDIM; ++d) { float v = xs[d][tid]; s = fmaf(v, v, s); }
        x2[b * NPTS + n0 + tid] = (s + 512.0f) * 512.0f;
    }
    int n = tid & 63, kk = tid >> 6;
    int nl = n & 15, ci = (n0 + n) >> 4;
    unsigned int hw[16];
    #pragma unroll
    for (int j = 0; j < 16; ++j) {
        unsigned short h0 = bf16rn(xs[kk * 32 + 2 * j][n]);
        unsigned short h1 = bf16rn(xs[kk * 32 + 2 * j + 1][n]);
        hw[j] = (unsigned)h0 | ((unsigned)h1 << 16);
    }
    char* cb = (char*)xt + ((size_t)b * NCHUNK + ci) * 4096;
    #pragma unroll
    for (int g = 0; g < 4; ++g)
        *(u32x4*)(cb + kk * 1024 + g * 256 + nl * 16) = *(u32x4*)(&hw[g * 4]);
    if (xfT) {
        float* fo = xfT + ((size_t)b * NPTS + n0 + n) * DDIM + kk * 32;
        #pragma unroll
        for (int g = 0; g < 8; ++g) {
            f32x4 v;
            v[0] = xs[kk * 32 + g * 4 + 0][n];
            v[1] = xs[kk * 32 + g * 4 + 1][n];
            v[2] = xs[kk * 32 + g * 4 + 2][n];
            v[3] = xs[kk * 32 + g * 4 + 3][n];
            *(f32x4*)(fo + g * 4) = v;
        }
    }
}

// ---------------- main MFMA kernel (EXACT round-11 kernel, proven) ----------------
// grid 2048 = (32 ptile x 16 b x 4 n-quarter) XCD-swizzled; block 256 = 4 waves
// = 4 psg, ONE n-stream of 49 chunks. 8 blocks/CU = 32 waves (one full fill).
// Counted-vmcnt(2): chunk t staged at body t-3; vmcnt then barrier => all slices landed.
__global__ __launch_bounds__(256, 8)
void proto_mfma(const unsigned short* __restrict__ xt,
                const unsigned short* __restrict__ pt,
                const float* __restrict__ x2,
                unsigned* __restrict__ k1w, unsigned* __restrict__ k2w) {
    // hand-placed LDS: [0,4K) x2s (784 used) | [4K,20K) As[4buf][4K]
    __shared__ __align__(16) char LDS[20480];
    float* x2s = (float*)LDS;
    char*  AsB = LDS + 4096;

    int lid = blockIdx.x;                      // 0..2047
    int sid = (lid & 7) * 256 + (lid >> 3);    // bijective XCD chunking (2048%8==0)
    int b = sid >> 7;                          // 2 b per XCD slice
    int rest = sid & 127;
    int pbase = (rest >> 2) * 64;              // 32 ptiles
    int q = rest & 3;

    int tid = threadIdx.x;
    int lane = tid & 63, psg = tid >> 6;       // 4 p-groups, shared n-stream
    int l15 = lane & 15, lg = lane >> 4;

    // B fragments: 4 named bf16x8 (16 VGPR), resident
    const unsigned short* bp = pt + (size_t)(pbase + psg * 16 + l15) * 128 + lg * 8;
    bf16x8 B0 = *(const bf16x8*)(bp);
    bf16x8 B1 = *(const bf16x8*)(bp + 32);
    bf16x8 B2 = *(const bf16x8*)(bp + 64);
    bf16x8 B3 = *(const bf16x8*)(bp + 96);

    const char* srcBase = (const char*)xt + ((size_t)b * NCHUNK + q * QCHUNK) * 4096;
    const char* aread = AsB + lane * 16;       // + buf*4096 + kk*1024
    const int qOfs = q * (QCHUNK * 16);
    const int nbBase = qOfs + lg * 4;          // + chunk*16 + rr

    unsigned K1 = 0xFFFFFFFFu, K2 = 0xFFFFFFFFu;

    // ---- prologue: x2 quarter slice (4 dword-DMAs, clamped) + chunks 0,1,2 ----
    {
        const float* xsrc = x2 + (size_t)b * NPTS + qOfs;
        #pragma unroll
        for (int r = 0; r < 4; ++r)
            gload_lds4(xsrc + min(r * 256 + psg * 64 + lane, QCHUNK * 16 - 1),
                       (char*)x2s + (r * 256 + psg * 64) * 4);
    }
    #pragma unroll
    for (int r = 0; r < 3; ++r)
        gload_lds16(srcBase + (size_t)r * 4096 + psg * 1024 + (size_t)lane * 16,
                    AsB + r * 4096 + psg * 1024);

    // Body: 1 chunk-DMA per wave per body; vmcnt(2) retires chunk T's loads
    // (in-order; x2 loads issued first retire first). Barrier AFTER the wait
    // => every wave's psg-slice of chunk T has landed for all readers.
#define PMF_BODY(T, U)                                                              \
    {                                                                               \
        asm volatile("s_waitcnt vmcnt(2)" ::: "memory");                            \
        __builtin_amdgcn_s_barrier();                                               \
        int cln = (T) + 3;                                                          \
        cln = cln > QCHUNK - 1 ? QCHUNK - 1 : cln;                                  \
        gload_lds16(srcBase + (size_t)cln * 4096 + psg * 1024 + (size_t)lane * 16,  \
                    AsB + (((U) + 3) & 3) * 4096 + psg * 1024);                     \
        f32x4 xv = *(const f32x4*)&x2s[(T) * 16 + lg * 4];                          \
        const char* ar = aread + (U) * 4096;                                        \
        f32x4 acc = {0.f, 0.f, 0.f, 0.f};                                           \
        __builtin_amdgcn_s_setprio(1);                                              \
        acc = __builtin_amdgcn_mfma_f32_16x16x32_bf16(*(const bf16x8*)(ar),        B0, acc, 0, 0, 0); \
        acc = __builtin_amdgcn_mfma_f32_16x16x32_bf16(*(const bf16x8*)(ar + 1024), B1, acc, 0, 0, 0); \
        acc = __builtin_amdgcn_mfma_f32_16x16x32_bf16(*(const bf16x8*)(ar + 2048), B2, acc, 0, 0, 0); \
        acc = __builtin_amdgcn_mfma_f32_16x16x32_bf16(*(const bf16x8*)(ar + 3072), B3, acc, 0, 0, 0); \
        __builtin_amdgcn_s_setprio(0);                                              \
        int nb = nbBase + (T) * 16;                                                 \
        _Pragma("unroll")                                                           \
        for (int rr = 0; rr < 4; ++rr) {                                            \
            float f = fmaf(acc[rr], -1024.f, xv[rr]);                               \
            unsigned k = ((unsigned)f << 12) | (unsigned)(nb + rr);                 \
            K2 = min(K2, max(K1, k));                                               \
            K1 = min(K1, k);                                                        \
        }                                                                           \
    }

    #pragma unroll 1
    for (int t0 = 0; t0 < 48; t0 += 4) {
        PMF_BODY(t0 + 0, 0)
        PMF_BODY(t0 + 1, 1)
        PMF_BODY(t0 + 2, 2)
        PMF_BODY(t0 + 3, 3)
    }
    PMF_BODY(48, 0)
#undef PMF_BODY

    // ---- reduce across the 4 row-groups (lanes l, l+16, l+32, l+48) ----
    #pragma unroll
    for (int m = 16; m <= 32; m <<= 1) {
        unsigned c1 = (unsigned)__shfl_xor((int)K1, m, 64);
        unsigned c2 = (unsigned)__shfl_xor((int)K2, m, 64);
        unsigned w  = max(K1, c1);
        K1 = min(K1, c1);
        K2 = min(w, min(K2, c2));
    }
    // each wave owns 16 distinct p -> direct global write, no cross-wave reduce
    if (lg == 0) {
        size_t o = ((size_t)b * 4 + q) * PPAD + pbase + psg * 16 + l15;
        k1w[o] = K1;
        k2w[o] = K2;
    }
}

// ---------------- exact fp32 fixup: derive half-top-2 (4 candidates) ----------------
// Quarter top-2s merge EXACTLY into half top-2s (disjoint n ranges):
//   top2(half) = top2(union(top2(qA), top2(qB))). d2 formula bit-identical.
template<int MODE>
__global__ __launch_bounds__(256)
void fixup(const float* __restrict__ x, const float* __restrict__ xfT,
           const float* __restrict__ proto,
           const unsigned* __restrict__ k1w, const unsigned* __restrict__ k2w,
           float* __restrict__ out) {
    int tid = threadIdx.x;
    int lane = tid & 63, wv = tid >> 6;
    long long pair = (long long)blockIdx.x * 4 + wv;
    if (pair >= (long long)BATCH * PROT) return;
    int b = (int)(pair / PROT), p = (int)(pair % PROT);
    unsigned a0 = k1w[((size_t)b * 4 + 0) * PPAD + p];
    unsigned a1 = k1w[((size_t)b * 4 + 1) * PPAD + p];
    unsigned a2 = k1w[((size_t)b * 4 + 2) * PPAD + p];
    unsigned a3 = k1w[((size_t)b * 4 + 3) * PPAD + p];
    unsigned c0 = k2w[((size_t)b * 4 + 0) * PPAD + p];
    unsigned c1 = k2w[((size_t)b * 4 + 1) * PPAD + p];
    unsigned c2 = k2w[((size_t)b * 4 + 2) * PPAD + p];
    unsigned c3 = k2w[((size_t)b * 4 + 3) * PPAD + p];
    int cand[4];
    cand[0] = (int)(min(a0, a1) & 0xFFFu);
    cand[1] = (int)(min(max(a0, a1), min(c0, c1)) & 0xFFFu);
    cand[2] = (int)(min(a2, a3) & 0xFFFu);
    cand[3] = (int)(min(max(a2, a3), min(c2, c3)) & 0xFFFu);

    int d0 = lane, d1 = lane + 64;
    float pa0 = proto[(size_t)p * DDIM + d0], pa1 = proto[(size_t)p * DDIM + d1];
    float sp2 = pa0 * pa0 + pa1 * pa1;
    float f0[4], f1[4], sxp[4], sx2[4];
    #pragma unroll
    for (int c = 0; c < 4; ++c) {
        int n = cand[c];
        float v0, v1;
        if (MODE == 0) {
            const float* f = xfT + ((size_t)b * NPTS + n) * DDIM;
            v0 = f[d0]; v1 = f[d1];
        } else {
            const float* xb = x + (size_t)b * DDIM * NPTS;
            v0 = xb[(size_t)d0 * NPTS + n]; v1 = xb[(size_t)d1 * NPTS + n];
        }
        f0[c] = v0; f1[c] = v1;
        sxp[c] = v0 * pa0 + v1 * pa1;
        sx2[c] = v0 * v0 + v1 * v1;
    }
    #pragma unroll
    for (int m = 1; m < 64; m <<= 1) {
        sp2 += __shfl_xor(sp2, m, 64);
        #pragma unroll
        for (int c = 0; c < 4; ++c) {
            sxp[c] += __shfl_xor(sxp[c], m, 64);
            sx2[c] += __shfl_xor(sx2[c], m, 64);
        }
    }
    float bd = 3e38f; int bn = 0x7FFFFFFF; int bc = 0;
    #pragma unroll
    for (int c = 0; c < 4; ++c) {
        float d2 = fmaxf(sx2[c] + sp2 - 2.f * sxp[c], 0.f);
        bool w = (d2 < bd) || (d2 == bd && cand[c] < bn);
        bd = w ? d2 : bd;
        bn = w ? cand[c] : bn;
        bc = w ? c : bc;
    }
    float dm = sqrtf(bd);
    float sim = logf((dm + 1.0f) / (dm + 1e-7f));
    if (lane == 0) {
        out[(size_t)b * PROT + p] = sim;
        out[(size_t)BATCH * PROT + (size_t)b * PROT + p] = dm;
    }
    float o0 = f0[0], o1 = f1[0];
    #pragma unroll
    for (int c = 1; c < 4; ++c) {
        o0 = (bc == c) ? f0[c] : o0;
        o1 = (bc == c) ? f1[c] : o1;
    }
    float* fo = out + (size_t)2 * BATCH * PROT + ((size_t)b * PROT + p) * DDIM;
    fo[d0] = o0;
    fo[d1] = o1;
}

// ================= fallback fp32 path (round-1, known-good) =================
#define TP 64
#define TN 64
__global__ void p2_kernel(const float* __restrict__ proto, float* __restrict__ p2) {
    int p = blockIdx.x * blockDim.x + threadIdx.x;
    if (p >= PROT) return;
    const float4* pr = reinterpret_cast<const float4*>(proto + (size_t)p * DDIM);
    float s = 0.f;
    #pragma unroll
    for (int i = 0; i < DDIM / 4; ++i) {
        float4 v = pr[i];
        s += v.x * v.x + v.y * v.y + v.z * v.z + v.w * v.w;
    }
    p2[p] = s;
}
__global__ void x2_kernel(const float* __restrict__ x, float* __restrict__ x2) {
    int idx = blockIdx.x * blockDim.x + threadIdx.x;
    if (idx >= BATCH * NPTS) return;
    int b = idx / NPTS, n = idx - b * NPTS;
    const float* xp = x + (size_t)b * DDIM * NPTS + n;
    float s = 0.f;
    #pragma unroll 8
    for (int d = 0; d < DDIM; ++d) { float v = xp[(size_t)d * NPTS]; s += v * v; }
    x2[idx] = s;
}
__global__ __launch_bounds__(256, 2)
void proto_main(const float* __restrict__ x, const float* __restrict__ proto,
                const float* __restrict__ p2, const float* __restrict__ x2,
                float* __restrict__ out) {
    __shared__ __align__(16) float xs[DDIM][TN];
    __shared__ __align__(16) float pst[DDIM][TP];
    __shared__ float p2s[TP];
    __shared__ float x2s[TN];
    __shared__ float red_d2[16][TP];
    __shared__ int   red_n[16][TP];
    __shared__ int   bestn_s[TP];
    const int b = blockIdx.y;
    const int pbase = blockIdx.x * TP;
    const int tid = threadIdx.x;
    {
        #pragma unroll
        for (int it = 0; it < (TP * DDIM / 4) / 256; ++it) {
            int idx = it * 256 + tid;
            int p = idx / (DDIM / 4);
            int dq = idx - p * (DDIM / 4);
            int gp = min(pbase + p, PROT - 1);
            float4 v = reinterpret_cast<const float4*>(proto)[(size_t)gp * (DDIM / 4) + dq];
            pst[dq * 4 + 0][p] = v.x; pst[dq * 4 + 1][p] = v.y;
            pst[dq * 4 + 2][p] = v.z; pst[dq * 4 + 3][p] = v.w;
        }
        if (tid < TP) p2s[tid] = p2[min(pbase + tid, PROT - 1)];
    }
    const int tn = tid >> 4;
    const int tp = tid & 15;
    float best[4]; int bestn[4];
    #pragma unroll
    for (int j = 0; j < 4; ++j) { best[j] = 1e30f; bestn[j] = 0; }
    for (int n0 = 0; n0 < NPTS; n0 += TN) {
        __syncthreads();
        {
            int r = tid >> 4, c = tid & 15;
            #pragma unroll
            for (int it = 0; it < 8; ++it) {
                int row = it * 16 + r;
                float4 v = *reinterpret_cast<const float4*>(
                    x + ((size_t)(b * DDIM + row)) * NPTS + n0 + c * 4);
                *reinterpret_cast<float4*>(&xs[row][c * 4]) = v;
            }
        }
        if (tid < TN) x2s[tid] = x2[b * NPTS + n0 + tid];
        __syncthreads();
        float acc[4][4];
        #pragma unroll
        for (int i = 0; i < 4; ++i)
            #pragma unroll
            for (int j = 0; j < 4; ++j) acc[i][j] = 0.f;
        #pragma unroll 16
        for (int d = 0; d < DDIM; ++d) {
            const float4 a = *reinterpret_cast<const float4*>(&xs[d][tn * 4]);
            const float4 bv = *reinterpret_cast<const float4*>(&pst[d][tp * 4]);
            const float av[4] = {a.x, a.y, a.z, a.w};
            const float bw[4] = {bv.x, bv.y, bv.z, bv.w};
            #pragma unroll
            for (int i = 0; i < 4; ++i)
                #pragma unroll
                for (int j = 0; j < 4; ++j) acc[i][j] = fmaf(av[i], bw[j], acc[i][j]);
        }
        #pragma unroll
        for (int i = 0; i < 4; ++i) {
            float xv = x2s[tn * 4 + i];
            int n = n0 + tn * 4 + i;
            #pragma unroll
            for (int j = 0; j < 4; ++j) {
                float d2 = xv + p2s[tp * 4 + j] - 2.0f * acc[i][j];
                if (d2 < best[j]) { best[j] = d2; bestn[j] = n; }
            }
        }
    }
    #pragma unroll
    for (int j = 0; j < 4; ++j) {
        red_d2[tn][tp * 4 + j] = best[j];
        red_n[tn][tp * 4 + j] = bestn[j];
    }
    __syncthreads();
    if (tid < TP) {
        float bd = red_d2[0][tid]; int bn = red_n[0][tid];
        #pragma unroll
        for (int t = 1; t < 16; ++t) {
            float dv = red_d2[t][tid]; int nv = red_n[t][tid];
            if (dv < bd || (dv == bd && nv < bn)) { bd = dv; bn = nv; }
        }
        int gp = pbase + tid;
        if (gp < PROT) {
            float d2c = fmaxf(bd, 0.f);
            float dmin = sqrtf(d2c);
            float sim = logf((dmin + 1.0f) / (dmin + 1e-7f));
            out[(size_t)b * PROT + gp] = sim;
            out[(size_t)BATCH * PROT + (size_t)b * PROT + gp] = dmin;
        }
        bestn_s[tid] = bn;
    }
    __syncthreads();
    {
        int pl = tid >> 2, dbase = (tid & 3) * 32;
        int gp = pbase + pl;
        if (gp < PROT) {
            int n = bestn_s[pl];
            float* dst = out + (size_t)2 * BATCH * PROT + ((size_t)(b * PROT + gp)) * DDIM + dbase;
            const float* src = x + ((size_t)(b * DDIM + dbase)) * NPTS + n;
            #pragma unroll 8
            for (int d = 0; d < 32; ++d) dst[d] = src[(size_t)d * NPTS];
        }
    }
}

extern "C" void kernel_launch(void* const* d_in, const int* in_sizes, int n_in,
                              void* d_out, int out_size, void* d_ws, size_t ws_size,
                              hipStream_t stream) {
    const float* x = (const float*)d_in[0];       // [16,128,56,56]
    const float* proto = (const float*)d_in[1];   // [1,2000,128]
    float* out = (float*)d_out;
    float* ws = (float*)d_ws;

    if (ws_size >= WS_MID) {
        bool big = (ws_size >= WS_BIG);
        float* x2 = ws + WS_X2;
        unsigned* k1w = (unsigned*)(ws + WS_K1);
        unsigned* k2w = (unsigned*)(ws + WS_K2);
        unsigned short* pt = (unsigned short*)(ws + WS_PT);
        unsigned short* xt = (unsigned short*)(ws + WS_XT);
        float* xfT = big ? (ws + WS_XFT) : nullptr;

        pp_fused<<<dim3(50, BATCH), 256, 0, stream>>>(x, proto, xt, pt, x2, xfT);
        proto_mfma<<<2048, 256, 0, stream>>>(xt, pt, x2, k1w, k2w);
        if (big)
            fixup<0><<<(BATCH * PROT) / 4, 256, 0, stream>>>(x, xfT, proto, k1w, k2w, out);
        else
            fixup<1><<<(BATCH * PROT) / 4, 256, 0, stream>>>(x, nullptr, proto, k1w, k2w, out);
    } else {
        float* p2 = ws;
        float* x2 = ws + 2048;
        p2_kernel<<<(PROT + 255) / 256, 256, 0, stream>>>(proto, p2);
        x2_kernel<<<(BATCH * NPTS + 255) / 256, 256, 0, stream>>>(x, x2);
        dim3 grid((PROT + TP - 1) / TP, BATCH);
        proto_main<<<grid, 256, 0, stream>>>(x, proto, p2, x2, out);
    }
}

// Round 15
// 78.435 us; speedup vs baseline: 1.9289x; 1.0419x over previous
//
#include <hip/hip_runtime.h>
#include <hip/hip_bf16.h>
#include <cmath>

#define DDIM 128
#define NPTS 3136   // 56*56
#define NCHUNK 196  // NPTS/16
#define QCHUNK 49   // chunks per n-quarter
#define BATCH 16
#define PROT 2000
#define PPAD 2048   // 16 tiles * 128

typedef __attribute__((ext_vector_type(8))) short bf16x8;
typedef __attribute__((ext_vector_type(4))) float f32x4;
typedef __attribute__((ext_vector_type(4))) unsigned int u32x4;

// ---- workspace layout (float/u32 slot indices) ----
#define WS_X2   0                      // 50176
#define WS_K1   50176                  // 131072 (16 b x 4 q x 2048)
#define WS_K2   181248                 // 131072
#define WS_PT   312320                 // 131072 slots (= 262144 shorts, 2048x128)
#define WS_XT   443392                 // 3211264 slots (= 16*196*4096 bytes)
#define WS_XFT  3654656                // 6422528 (16*3136*128 f32)
#define WS_MID  ((size_t)3654656 * 4)
#define WS_BIG  ((size_t)10077184 * 4)

// ---------------- bf16 helpers ----------------
__device__ inline unsigned short bf16rn(float a) {
    unsigned u = __float_as_uint(a);
    unsigned r = u + 0x7FFFu + ((u >> 16) & 1u);
    return (unsigned short)(r >> 16);
}

__device__ __forceinline__ void gload_lds16(const void* g, void* l) {
    __builtin_amdgcn_global_load_lds(
        (const __attribute__((address_space(1))) void*)g,
        (__attribute__((address_space(3))) void*)l, 16, 0, 0);
}
__device__ __forceinline__ void gload_lds4(const void* g, void* l) {
    __builtin_amdgcn_global_load_lds(
        (const __attribute__((address_space(1))) void*)g,
        (__attribute__((address_space(3))) void*)l, 4, 0, 0);
}

// ---------------- fused pre-pass (unchanged from r14, proven) ----------------
__global__ __launch_bounds__(256)
void pp_fused(const float* __restrict__ x, const float* __restrict__ proto,
              unsigned short* __restrict__ xt, unsigned short* __restrict__ pt,
              float* __restrict__ x2, float* __restrict__ xfT) {
    int tid = threadIdx.x;
    if (blockIdx.x == 49) {               // prototype part: 8 blocks x 256 = 2048
        int by = blockIdx.y;
        if (by >= 8) return;
        int p = by * 256 + tid;           // 0..2047
        int ps = min(p, PROT - 1);
        const float* src = proto + (size_t)ps * DDIM;
        unsigned short* dst = pt + (size_t)p * 128;
        for (int j = 0; j < DDIM; ++j) dst[j] = bf16rn(src[j]);
        return;
    }
    __shared__ float xs[DDIM][64];
    int b = blockIdx.y;
    int n0 = blockIdx.x * 64;
    {
        int r = tid >> 4, c = tid & 15;
        #pragma unroll
        for (int it = 0; it < 8; ++it) {
            int row = it * 16 + r;
            f32x4 v = *(const f32x4*)(x + ((size_t)(b * DDIM + row)) * NPTS + n0 + c * 4);
            *(f32x4*)(&xs[row][c * 4]) = v;
        }
    }
    __syncthreads();
    if (tid < 64) {
        float s = 0.f;
        #pragma unroll 8
        for (int d = 0; d < DDIM; ++d) { float v = xs[d][tid]; s = fmaf(v, v, s); }
        x2[b * NPTS + n0 + tid] = (s + 512.0f) * 512.0f;
    }
    int n = tid & 63, kk = tid >> 6;
    int nl = n & 15, ci = (n0 + n) >> 4;
    unsigned int hw[16];
    #pragma unroll
    for (int j = 0; j < 16; ++j) {
        unsigned short h0 = bf16rn(xs[kk * 32 + 2 * j][n]);
        unsigned short h1 = bf16rn(xs[kk * 32 + 2 * j + 1][n]);
        hw[j] = (unsigned)h0 | ((unsigned)h1 << 16);
    }
    char* cb = (char*)xt + ((size_t)b * NCHUNK + ci) * 4096;
    #pragma unroll
    for (int g = 0; g < 4; ++g)
        *(u32x4*)(cb + kk * 1024 + g * 256 + nl * 16) = *(u32x4*)(&hw[g * 4]);
    if (xfT) {
        float* fo = xfT + ((size_t)b * NPTS + n0 + n) * DDIM + kk * 32;
        #pragma unroll
        for (int g = 0; g < 8; ++g) {
            f32x4 v;
            v[0] = xs[kk * 32 + g * 4 + 0][n];
            v[1] = xs[kk * 32 + g * 4 + 1][n];
            v[2] = xs[kk * 32 + g * 4 + 2][n];
            v[3] = xs[kk * 32 + g * 4 + 3][n];
            *(f32x4*)(fo + g * 4) = v;
        }
    }
}

// ---------------- main MFMA kernel (r11/r14 skeleton, 32 p per wave) ----------------
// grid 1024 = (16 ptile x 16 b x 4 n-quarter) XCD-swizzled; block 256 = 4 waves
// = 4 psg x 32 p each (TWO B-fragment sets). ONE n-stream of 49 chunks.
// Counted-vmcnt(2): chunk t staged at body t-3; vmcnt then barrier => all slices landed.
// Per-body fixed overhead (sync, addressing, stage DMA, A ds_reads) now amortizes
// over 2x the output elements. launch_bounds (256,4): 128-VGPR budget, no spill.
__global__ __launch_bounds__(256, 4)
void proto_mfma(const unsigned short* __restrict__ xt,
                const unsigned short* __restrict__ pt,
                const float* __restrict__ x2,
                unsigned* __restrict__ k1w, unsigned* __restrict__ k2w) {
    // hand-placed LDS: [0,4K) x2s (784 used) | [4K,20K) As[4buf][4K]
    __shared__ __align__(16) char LDS[20480];
    float* x2s = (float*)LDS;
    char*  AsB = LDS + 4096;

    int lid = blockIdx.x;                      // 0..1023
    int sid = (lid & 7) * 128 + (lid >> 3);    // bijective XCD chunking (1024%8==0)
    int b = sid >> 6;                          // 16 b
    int rest = sid & 63;
    int pbase = (rest >> 2) * 128;             // 16 ptiles of 128
    int q = rest & 3;

    int tid = threadIdx.x;
    int lane = tid & 63, psg = tid >> 6;       // 4 p-groups of 32p, shared n-stream
    int l15 = lane & 15, lg = lane >> 4;

    // B fragments: 2 sets x 4 named bf16x8 (32 VGPR), resident
    const unsigned short* bpa = pt + (size_t)(pbase + psg * 32 + l15) * 128 + lg * 8;
    const unsigned short* bpb = bpa + (size_t)16 * 128;
    bf16x8 Ba0 = *(const bf16x8*)(bpa);
    bf16x8 Ba1 = *(const bf16x8*)(bpa + 32);
    bf16x8 Ba2 = *(const bf16x8*)(bpa + 64);
    bf16x8 Ba3 = *(const bf16x8*)(bpa + 96);
    bf16x8 Bb0 = *(const bf16x8*)(bpb);
    bf16x8 Bb1 = *(const bf16x8*)(bpb + 32);
    bf16x8 Bb2 = *(const bf16x8*)(bpb + 64);
    bf16x8 Bb3 = *(const bf16x8*)(bpb + 96);

    const char* srcBase = (const char*)xt + ((size_t)b * NCHUNK + q * QCHUNK) * 4096;
    const char* aread = AsB + lane * 16;       // + buf*4096 + kk*1024
    const int qOfs = q * (QCHUNK * 16);
    const int nbBase = qOfs + lg * 4;          // + chunk*16 + rr

    unsigned K1a = 0xFFFFFFFFu, K2a = 0xFFFFFFFFu;
    unsigned K1b = 0xFFFFFFFFu, K2b = 0xFFFFFFFFu;

    // ---- prologue: x2 quarter slice (4 dword-DMAs, clamped) + chunks 0,1,2 ----
    {
        const float* xsrc = x2 + (size_t)b * NPTS + qOfs;
        #pragma unroll
        for (int r = 0; r < 4; ++r)
            gload_lds4(xsrc + min(r * 256 + psg * 64 + lane, QCHUNK * 16 - 1),
                       (char*)x2s + (r * 256 + psg * 64) * 4);
    }
    #pragma unroll
    for (int r = 0; r < 3; ++r)
        gload_lds16(srcBase + (size_t)r * 4096 + psg * 1024 + (size_t)lane * 16,
                    AsB + r * 4096 + psg * 1024);

    // Body: 1 chunk-DMA per wave per body; vmcnt(2) retires chunk T's loads
    // (in-order). Barrier AFTER the wait => chunk T visible to all readers.
#define PMF_TRACK(ACC, XV, NB, K1, K2)                                              \
        _Pragma("unroll")                                                           \
        for (int rr = 0; rr < 4; ++rr) {                                            \
            float f = fmaf((ACC)[rr], -1024.f, (XV)[rr]);                           \
            unsigned k = ((unsigned)f << 12) | (unsigned)((NB) + rr);               \
            K2 = min(K2, max(K1, k));                                               \
            K1 = min(K1, k);                                                        \
        }

#define PMF_BODY(T, U)                                                              \
    {                                                                               \
        asm volatile("s_waitcnt vmcnt(2)" ::: "memory");                            \
        __builtin_amdgcn_s_barrier();                                               \
        int cln = (T) + 3;                                                          \
        cln = cln > QCHUNK - 1 ? QCHUNK - 1 : cln;                                  \
        gload_lds16(srcBase + (size_t)cln * 4096 + psg * 1024 + (size_t)lane * 16,  \
                    AsB + (((U) + 3) & 3) * 4096 + psg * 1024);                     \
        f32x4 xv = *(const f32x4*)&x2s[(T) * 16 + lg * 4];                          \
        const char* ar = aread + (U) * 4096;                                        \
        bf16x8 A0 = *(const bf16x8*)(ar);                                           \
        bf16x8 A1 = *(const bf16x8*)(ar + 1024);                                    \
        bf16x8 A2 = *(const bf16x8*)(ar + 2048);                                    \
        bf16x8 A3 = *(const bf16x8*)(ar + 3072);                                    \
        f32x4 accA = {0.f, 0.f, 0.f, 0.f};                                          \
        f32x4 accB = {0.f, 0.f, 0.f, 0.f};                                          \
        __builtin_amdgcn_s_setprio(1);                                              \
        accA = __builtin_amdgcn_mfma_f32_16x16x32_bf16(A0, Ba0, accA, 0, 0, 0);     \
        accB = __builtin_amdgcn_mfma_f32_16x16x32_bf16(A0, Bb0, accB, 0, 0, 0);     \
        accA = __builtin_amdgcn_mfma_f32_16x16x32_bf16(A1, Ba1, accA, 0, 0, 0);     \
        accB = __builtin_amdgcn_mfma_f32_16x16x32_bf16(A1, Bb1, accB, 0, 0, 0);     \
        accA = __builtin_amdgcn_mfma_f32_16x16x32_bf16(A2, Ba2, accA, 0, 0, 0);     \
        accB = __builtin_amdgcn_mfma_f32_16x16x32_bf16(A2, Bb2, accB, 0, 0, 0);     \
        accA = __builtin_amdgcn_mfma_f32_16x16x32_bf16(A3, Ba3, accA, 0, 0, 0);     \
        accB = __builtin_amdgcn_mfma_f32_16x16x32_bf16(A3, Bb3, accB, 0, 0, 0);     \
        __builtin_amdgcn_s_setprio(0);                                              \
        int nb = nbBase + (T) * 16;                                                 \
        PMF_TRACK(accA, xv, nb, K1a, K2a)                                           \
        PMF_TRACK(accB, xv, nb, K1b, K2b)                                           \
    }

    #pragma unroll 1
    for (int t0 = 0; t0 < 48; t0 += 4) {
        PMF_BODY(t0 + 0, 0)
        PMF_BODY(t0 + 1, 1)
        PMF_BODY(t0 + 2, 2)
        PMF_BODY(t0 + 3, 3)
    }
    PMF_BODY(48, 0)
#undef PMF_BODY
#undef PMF_TRACK

    // ---- reduce across the 4 row-groups (lanes l, l+16, l+32, l+48) ----
    #pragma unroll
    for (int m = 16; m <= 32; m <<= 1) {
        unsigned c1a = (unsigned)__shfl_xor((int)K1a, m, 64);
        unsigned c2a = (unsigned)__shfl_xor((int)K2a, m, 64);
        unsigned wa  = max(K1a, c1a);
        K1a = min(K1a, c1a);
        K2a = min(wa, min(K2a, c2a));
        unsigned c1b = (unsigned)__shfl_xor((int)K1b, m, 64);
        unsigned c2b = (unsigned)__shfl_xor((int)K2b, m, 64);
        unsigned wb  = max(K1b, c1b);
        K1b = min(K1b, c1b);
        K2b = min(wb, min(K2b, c2b));
    }
    // each wave owns 32 distinct p -> direct global writes, no cross-wave reduce
    if (lg == 0) {
        size_t o = ((size_t)b * 4 + q) * PPAD + pbase + psg * 32 + l15;
        k1w[o] = K1a;
        k2w[o] = K2a;
        k1w[o + 16] = K1b;
        k2w[o + 16] = K2b;
    }
}

// ---------------- exact fp32 fixup: derive half-top-2 (4 candidates) ----------------
// Quarter top-2s merge EXACTLY into half top-2s (disjoint n ranges):
//   top2(half) = top2(union(top2(qA), top2(qB))). d2 formula bit-identical.
template<int MODE>
__global__ __launch_bounds__(256)
void fixup(const float* __restrict__ x, const float* __restrict__ xfT,
           const float* __restrict__ proto,
           const unsigned* __restrict__ k1w, const unsigned* __restrict__ k2w,
           float* __restrict__ out) {
    int tid = threadIdx.x;
    int lane = tid & 63, wv = tid >> 6;
    long long pair = (long long)blockIdx.x * 4 + wv;
    if (pair >= (long long)BATCH * PROT) return;
    int b = (int)(pair / PROT), p = (int)(pair % PROT);
    unsigned a0 = k1w[((size_t)b * 4 + 0) * PPAD + p];
    unsigned a1 = k1w[((size_t)b * 4 + 1) * PPAD + p];
    unsigned a2 = k1w[((size_t)b * 4 + 2) * PPAD + p];
    unsigned a3 = k1w[((size_t)b * 4 + 3) * PPAD + p];
    unsigned c0 = k2w[((size_t)b * 4 + 0) * PPAD + p];
    unsigned c1 = k2w[((size_t)b * 4 + 1) * PPAD + p];
    unsigned c2 = k2w[((size_t)b * 4 + 2) * PPAD + p];
    unsigned c3 = k2w[((size_t)b * 4 + 3) * PPAD + p];
    int cand[4];
    cand[0] = (int)(min(a0, a1) & 0xFFFu);
    cand[1] = (int)(min(max(a0, a1), min(c0, c1)) & 0xFFFu);
    cand[2] = (int)(min(a2, a3) & 0xFFFu);
    cand[3] = (int)(min(max(a2, a3), min(c2, c3)) & 0xFFFu);

    int d0 = lane, d1 = lane + 64;
    float pa0 = proto[(size_t)p * DDIM + d0], pa1 = proto[(size_t)p * DDIM + d1];
    float sp2 = pa0 * pa0 + pa1 * pa1;
    float f0[4], f1[4], sxp[4], sx2[4];
    #pragma unroll
    for (int c = 0; c < 4; ++c) {
        int n = cand[c];
        float v0, v1;
        if (MODE == 0) {
            const float* f = xfT + ((size_t)b * NPTS + n) * DDIM;
            v0 = f[d0]; v1 = f[d1];
        } else {
            const float* xb = x + (size_t)b * DDIM * NPTS;
            v0 = xb[(size_t)d0 * NPTS + n]; v1 = xb[(size_t)d1 * NPTS + n];
        }
        f0[c] = v0; f1[c] = v1;
        sxp[c] = v0 * pa0 + v1 * pa1;
        sx2[c] = v0 * v0 + v1 * v1;
    }
    #pragma unroll
    for (int m = 1; m < 64; m <<= 1) {
        sp2 += __shfl_xor(sp2, m, 64);
        #pragma unroll
        for (int c = 0; c < 4; ++c) {
            sxp[c] += __shfl_xor(sxp[c], m, 64);
            sx2[c] += __shfl_xor(sx2[c], m, 64);
        }
    }
    float bd = 3e38f; int bn = 0x7FFFFFFF; int bc = 0;
    #pragma unroll
    for (int c = 0; c < 4; ++c) {
        float d2 = fmaxf(sx2[c] + sp2 - 2.f * sxp[c], 0.f);
        bool w = (d2 < bd) || (d2 == bd && cand[c] < bn);
        bd = w ? d2 : bd;
        bn = w ? cand[c] : bn;
        bc = w ? c : bc;
    }
    float dm = sqrtf(bd);
    float sim = logf((dm + 1.0f) / (dm + 1e-7f));
    if (lane == 0) {
        out[(size_t)b * PROT + p] = sim;
        out[(size_t)BATCH * PROT + (size_t)b * PROT + p] = dm;
    }
    float o0 = f0[0], o1 = f1[0];
    #pragma unroll
    for (int c = 1; c < 4; ++c) {
        o0 = (bc == c) ? f0[c] : o0;
        o1 = (bc == c) ? f1[c] : o1;
    }
    float* fo = out + (size_t)2 * BATCH * PROT + ((size_t)b * PROT + p) * DDIM;
    fo[d0] = o0;
    fo[d1] = o1;
}

// ================= fallback fp32 path (round-1, known-good) =================
#define TP 64
#define TN 64
__global__ void p2_kernel(const float* __restrict__ proto, float* __restrict__ p2) {
    int p = blockIdx.x * blockDim.x + threadIdx.x;
    if (p >= PROT) return;
    const float4* pr = reinterpret_cast<const float4*>(proto + (size_t)p * DDIM);
    float s = 0.f;
    #pragma unroll
    for (int i = 0; i < DDIM / 4; ++i) {
        float4 v = pr[i];
        s += v.x * v.x + v.y * v.y + v.z * v.z + v.w * v.w;
    }
    p2[p] = s;
}
__global__ void x2_kernel(const float* __restrict__ x, float* __restrict__ x2) {
    int idx = blockIdx.x * blockDim.x + threadIdx.x;
    if (idx >= BATCH * NPTS) return;
    int b = idx / NPTS, n = idx - b * NPTS;
    const float* xp = x + (size_t)b * DDIM * NPTS + n;
    float s = 0.f;
    #pragma unroll 8
    for (int d = 0; d < DDIM; ++d) { float v = xp[(size_t)d * NPTS]; s += v * v; }
    x2[idx] = s;
}
__global__ __launch_bounds__(256, 2)
void proto_main(const float* __restrict__ x, const float* __restrict__ proto,
                const float* __restrict__ p2, const float* __restrict__ x2,
                float* __restrict__ out) {
    __shared__ __align__(16) float xs[DDIM][TN];
    __shared__ __align__(16) float pst[DDIM][TP];
    __shared__ float p2s[TP];
    __shared__ float x2s[TN];
    __shared__ float red_d2[16][TP];
    __shared__ int   red_n[16][TP];
    __shared__ int   bestn_s[TP];
    const int b = blockIdx.y;
    const int pbase = blockIdx.x * TP;
    const int tid = threadIdx.x;
    {
        #pragma unroll
        for (int it = 0; it < (TP * DDIM / 4) / 256; ++it) {
            int idx = it * 256 + tid;
            int p = idx / (DDIM / 4);
            int dq = idx - p * (DDIM / 4);
            int gp = min(pbase + p, PROT - 1);
            float4 v = reinterpret_cast<const float4*>(proto)[(size_t)gp * (DDIM / 4) + dq];
            pst[dq * 4 + 0][p] = v.x; pst[dq * 4 + 1][p] = v.y;
            pst[dq * 4 + 2][p] = v.z; pst[dq * 4 + 3][p] = v.w;
        }
        if (tid < TP) p2s[tid] = p2[min(pbase + tid, PROT - 1)];
    }
    const int tn = tid >> 4;
    const int tp = tid & 15;
    float best[4]; int bestn[4];
    #pragma unroll
    for (int j = 0; j < 4; ++j) { best[j] = 1e30f; bestn[j] = 0; }
    for (int n0 = 0; n0 < NPTS; n0 += TN) {
        __syncthreads();
        {
            int r = tid >> 4, c = tid & 15;
            #pragma unroll
            for (int it = 0; it < 8; ++it) {
                int row = it * 16 + r;
                float4 v = *reinterpret_cast<const float4*>(
                    x + ((size_t)(b * DDIM + row)) * NPTS + n0 + c * 4);
                *reinterpret_cast<float4*>(&xs[row][c * 4]) = v;
            }
        }
        if (tid < TN) x2s[tid] = x2[b * NPTS + n0 + tid];
        __syncthreads();
        float acc[4][4];
        #pragma unroll
        for (int i = 0; i < 4; ++i)
            #pragma unroll
            for (int j = 0; j < 4; ++j) acc[i][j] = 0.f;
        #pragma unroll 16
        for (int d = 0; d < DDIM; ++d) {
            const float4 a = *reinterpret_cast<const float4*>(&xs[d][tn * 4]);
            const float4 bv = *reinterpret_cast<const float4*>(&pst[d][tp * 4]);
            const float av[4] = {a.x, a.y, a.z, a.w};
            const float bw[4] = {bv.x, bv.y, bv.z, bv.w};
            #pragma unroll
            for (int i = 0; i < 4; ++i)
                #pragma unroll
                for (int j = 0; j < 4; ++j) acc[i][j] = fmaf(av[i], bw[j], acc[i][j]);
        }
        #pragma unroll
        for (int i = 0; i < 4; ++i) {
            float xv = x2s[tn * 4 + i];
            int n = n0 + tn * 4 + i;
            #pragma unroll
            for (int j = 0; j < 4; ++j) {
                float d2 = xv + p2s[tp * 4 + j] - 2.0f * acc[i][j];
                if (d2 < best[j]) { best[j] = d2; bestn[j] = n; }
            }
        }
    }
    #pragma unroll
    for (int j = 0; j < 4; ++j) {
        red_d2[tn][tp * 4 + j] = best[j];
        red_n[tn][tp * 4 + j] = bestn[j];
    }
    __syncthreads();
    if (tid < TP) {
        float bd = red_d2[0][tid]; int bn = red_n[0][tid];
        #pragma unroll
        for (int t = 1; t < 16; ++t) {
            float dv = red_d2[t][tid]; int nv = red_n[t][tid];
            if (dv < bd || (dv == bd && nv < bn)) { bd = dv; bn = nv; }
        }
        int gp = pbase + tid;
        if (gp < PROT) {
            float d2c = fmaxf(bd, 0.f);
            float dmin = sqrtf(d2c);
            float sim = logf((dmin + 1.0f) / (dmin + 1e-7f));
            out[(size_t)b * PROT + gp] = sim;
            out[(size_t)BATCH * PROT + (size_t)b * PROT + gp] = dmin;
        }
        bestn_s[tid] = bn;
    }
    __syncthreads();
    {
        int pl = tid >> 2, dbase = (tid & 3) * 32;
        int gp = pbase + pl;
        if (gp < PROT) {
            int n = bestn_s[pl];
            float* dst = out + (size_t)2 * BATCH * PROT + ((size_t)(b * PROT + gp)) * DDIM + dbase;
            const float* src = x + ((size_t)(b * DDIM + dbase)) * NPTS + n;
            #pragma unroll 8
            for (int d = 0; d < 32; ++d) dst[d] = src[(size_t)d * NPTS];
        }
    }
}

extern "C" void kernel_launch(void* const* d_in, const int* in_sizes, int n_in,
                              void* d_out, int out_size, void* d_ws, size_t ws_size,
                              hipStream_t stream) {
    const float* x = (const float*)d_in[0];       // [16,128,56,56]
    const float* proto = (const float*)d_in[1];   // [1,2000,128]
    float* out = (float*)d_out;
    float* ws = (float*)d_ws;

    if (ws_size >= WS_MID) {
        bool big = (ws_size >= WS_BIG);
        float* x2 = ws + WS_X2;
        unsigned* k1w = (unsigned*)(ws + WS_K1);
        unsigned* k2w = (unsigned*)(ws + WS_K2);
        unsigned short* pt = (unsigned short*)(ws + WS_PT);
        unsigned short* xt = (unsigned short*)(ws + WS_XT);
        float* xfT = big ? (ws + WS_XFT) : nullptr;

        pp_fused<<<dim3(50, BATCH), 256, 0, stream>>>(x, proto, xt, pt, x2, xfT);
        proto_mfma<<<1024, 256, 0, stream>>>(xt, pt, x2, k1w, k2w);
        if (big)
            fixup<0><<<(BATCH * PROT) / 4, 256, 0, stream>>>(x, xfT, proto, k1w, k2w, out);
        else
            fixup<1><<<(BATCH * PROT) / 4, 256, 0, stream>>>(x, nullptr, proto, k1w, k2w, out);
    } else {
        float* p2 = ws;
        float* x2 = ws + 2048;
        p2_kernel<<<(PROT + 255) / 256, 256, 0, stream>>>(proto, p2);
        x2_kernel<<<(BATCH * NPTS + 255) / 256, 256, 0, stream>>>(x, x2);
        dim3 grid((PROT + TP - 1) / TP, BATCH);
        proto_main<<<grid, 256, 0, stream>>>(x, proto, p2, x2, out);
    }
}